// Round 1
// baseline (1118.299 us; speedup 1.0000x reference)
//
#include <hip/hip_runtime.h>
#include <hip/hip_fp16.h>
#include <stdint.h>

#define Nn 50000
#define Ee 1600000
#define Gg 64
#define NBUK 1563   // ceil(Nn/32): bucket = 32 consecutive dst nodes
#define NBUK_PAD 1564

// ---------------- one-time CSR build ----------------
__global__ void k_hist(const int* __restrict__ ei, int* __restrict__ deg) {
    int e = blockIdx.x * blockDim.x + threadIdx.x;
    if (e < Ee) atomicAdd(&deg[ei[Ee + e]], 1);
}

__global__ void k_scan1(const int* __restrict__ deg, int* __restrict__ row_ptr,
                        int* __restrict__ bsum) {
    __shared__ int buf[256];
    int i = blockIdx.x * 256 + threadIdx.x;
    int v = (i < Nn) ? deg[i] : 0;
    buf[threadIdx.x] = v;
    __syncthreads();
    for (int off = 1; off < 256; off <<= 1) {
        int t = (threadIdx.x >= off) ? buf[threadIdx.x - off] : 0;
        __syncthreads();
        buf[threadIdx.x] += t;
        __syncthreads();
    }
    if (i < Nn) row_ptr[i + 1] = buf[threadIdx.x];  // block-local inclusive
    if (threadIdx.x == 255) bsum[blockIdx.x] = buf[255];
}

__global__ void k_scan2(int* __restrict__ bsum, int nb) {
    __shared__ int buf[256];
    int v = (threadIdx.x < nb) ? bsum[threadIdx.x] : 0;
    buf[threadIdx.x] = v;
    __syncthreads();
    for (int off = 1; off < 256; off <<= 1) {
        int t = (threadIdx.x >= off) ? buf[threadIdx.x - off] : 0;
        __syncthreads();
        buf[threadIdx.x] += t;
        __syncthreads();
    }
    if (threadIdx.x < nb) bsum[threadIdx.x] = buf[threadIdx.x];  // inclusive
}

__global__ void k_scan3(int* __restrict__ row_ptr, const int* __restrict__ bsum) {
    int i = blockIdx.x * 256 + threadIdx.x;  // i in [0, Nn]
    if (i > Nn) return;
    if (i == 0) { row_ptr[0] = 0; return; }
    int b = (i - 1) >> 8;
    if (b > 0) row_ptr[i] += bsum[b - 1];
}

// fallback path (workspace too small for bucketed sort): original scatter
__global__ void k_scatter(const int* __restrict__ ei, int* __restrict__ cursor,
                          int* __restrict__ src_perm, int* __restrict__ eperm) {
    int e = blockIdx.x * blockDim.x + threadIdx.x;
    if (e >= Ee) return;
    int dst = ei[Ee + e];
    int pos = atomicAdd(&cursor[dst], 1);
    src_perm[pos] = ei[e];
    eperm[pos] = e;
}

__global__ void k_easort(const float* __restrict__ ea, const int* __restrict__ eperm,
                         __half* __restrict__ ea_h) {
    long t = (long)blockIdx.x * blockDim.x + threadIdx.x;  // E*4 quarter-rows
    if (t >= (long)Ee * 4) return;
    long idx = t >> 2;
    int e = eperm[idx];
    float4 v = ((const float4*)ea)[(long)e * 4 + (t & 3)];
    __half2 lo = __floats2half2_rn(v.x, v.y);
    __half2 hi = __floats2half2_rn(v.z, v.w);
    ((__half2*)ea_h)[t * 2]     = lo;
    ((__half2*)ea_h)[t * 2 + 1] = hi;
}

// ---- bucketed two-pass scatter (main path) ----
// bucket cursors start at the bucket's CSR base (row_ptr[32*b]) so pass A
// appends directly into the final array's bucket span (unordered within it).
__global__ void k_binit(const int* __restrict__ row_ptr, int* __restrict__ bcur) {
    int b = blockIdx.x * 256 + threadIdx.x;
    if (b < NBUK) bcur[b] = row_ptr[b * 32];
}

// Pass A: pack (dst|src|e) into u64, append to bucket region.
// Appends to 1563 sequentially-filling regions -> L2 write-combines to full
// lines (vs the old fully-random 4B scatter's ~11x write amplification).
__global__ void k_bucketA(const int* __restrict__ ei, int* __restrict__ bcur,
                          unsigned long long* __restrict__ tmp) {
    int e = blockIdx.x * blockDim.x + threadIdx.x;
    if (e >= Ee) return;
    int src = ei[e];
    int dst = ei[Ee + e];
    int pos = atomicAdd(&bcur[dst >> 5], 1);
    tmp[pos] = ((unsigned long long)(unsigned)dst << 37)
             | ((unsigned long long)(unsigned)src << 21)
             | (unsigned long long)(unsigned)e;
}

// Pass B: coalesced read of tmp; final pos lands inside the bucket's
// contiguous CSR span (L2-local, write-combined). Fuses the ea row permute
// + fp16 convert (kills k_easort + the eperm array writes entirely).
__global__ void k_bucketB(const unsigned long long* __restrict__ tmp,
                          int* __restrict__ cursor, int* __restrict__ src_perm,
                          const float* __restrict__ ea, __half* __restrict__ ea_h) {
    int t = blockIdx.x * blockDim.x + threadIdx.x;
    if (t >= Ee) return;
    unsigned long long p = tmp[t];
    int dst = (int)(p >> 37);
    int src = (int)((p >> 21) & 0xFFFFull);
    int e   = (int)(p & 0x1FFFFFull);
    int pos = atomicAdd(&cursor[dst], 1);
    src_perm[pos] = src;
    const float4* er = (const float4*)(ea + (size_t)e * 16);
    float4 v0 = er[0], v1 = er[1], v2 = er[2], v3 = er[3];
    __half2 h0 = __floats2half2_rn(v0.x, v0.y), h1 = __floats2half2_rn(v0.z, v0.w);
    __half2 h2 = __floats2half2_rn(v1.x, v1.y), h3 = __floats2half2_rn(v1.z, v1.w);
    __half2 h4 = __floats2half2_rn(v2.x, v2.y), h5 = __floats2half2_rn(v2.z, v2.w);
    __half2 h6 = __floats2half2_rn(v3.x, v3.y), h7 = __floats2half2_rn(v3.z, v3.w);
    uint4 a = make_uint4(*(unsigned*)&h0, *(unsigned*)&h1,
                         *(unsigned*)&h2, *(unsigned*)&h3);
    uint4 b = make_uint4(*(unsigned*)&h4, *(unsigned*)&h5,
                         *(unsigned*)&h6, *(unsigned*)&h7);
    uint4* o = (uint4*)(ea_h + (size_t)pos * 16);  // ea_h base 64B-aligned
    o[0] = a;
    o[1] = b;
}

__global__ void k_gbound(const int* __restrict__ batch, int* __restrict__ gstart) {
    int n = blockIdx.x * blockDim.x + threadIdx.x;
    if (n >= Nn) return;
    int b = batch[n];
    if (n == 0) { for (int g = 0; g <= b; ++g) gstart[g] = 0; }
    else { int bp = batch[n - 1]; for (int g = bp + 1; g <= b; ++g) gstart[g] = n; }
    if (n == Nn - 1) { for (int g = b + 1; g <= Gg; ++g) gstart[g] = Nn; }
}

// ---------------- node kernels ----------------
// h = relu(x @ Wn + bn). Register-blocked: x-tile in LDS, Wn chunk in regs.
// k0 loop NOT unrolled (full unroll -> load hoisting -> spill, see R4/R5).
__global__ __launch_bounds__(256) void k_encode(const float* __restrict__ x,
                         const float* __restrict__ Wn,
                         const float* __restrict__ bn, float* __restrict__ h) {
    __shared__ float sx[64 * 32];
    int base = blockIdx.x * 64;
    for (int i = threadIdx.x; i < 512; i += 256) {        // 64 rows x 32 cols, float4
        int off = i * 4, row = off >> 5;
        float4 v = (base + row < Nn) ? ((const float4*)(x))[(base * 32 + off) >> 2]
                                     : make_float4(0.f, 0.f, 0.f, 0.f);
        ((float4*)sx)[i] = v;
    }
    __syncthreads();
    int lane = threadIdx.x & 63, wv = threadIdx.x >> 6;
    float acc[16];
    float b = bn[lane];
#pragma unroll
    for (int nn = 0; nn < 16; ++nn) acc[nn] = b;
#pragma unroll 1
    for (int k0 = 0; k0 < 32; k0 += 4) {
        float w0 = Wn[(k0 + 0) * 64 + lane];
        float w1 = Wn[(k0 + 1) * 64 + lane];
        float w2 = Wn[(k0 + 2) * 64 + lane];
        float w3 = Wn[(k0 + 3) * 64 + lane];
#pragma unroll
        for (int nn = 0; nn < 16; ++nn) {
            int row = wv * 16 + nn;
            float4 hv = *(const float4*)&sx[row * 32 + k0];
            acc[nn] = fmaf(hv.x, w0, fmaf(hv.y, w1, fmaf(hv.z, w2, fmaf(hv.w, w3, acc[nn]))));
        }
    }
#pragma unroll
    for (int nn = 0; nn < 16; ++nn) {
        int n = base + wv * 16 + nn;
        if (n < Nn) h[(size_t)n * 64 + lane] = fmaxf(acc[nn], 0.f);
    }
}

// All 3 layers' Wqm/bqm in one launch (block = layer).
__global__ void k_wqm3(const float* __restrict__ Wq_all, const float* __restrict__ bq_all,
                       const float* __restrict__ We_all, float* __restrict__ Wqm3,
                       float* __restrict__ bqm3) {
    int l = blockIdx.x;
    const float* Wq = Wq_all + l * 4096;
    const float* bq = bq_all + l * 64;
    const float* We = We_all + l * 1024;
    float* Wqm = Wqm3 + l * 4096;
    float* bqm = bqm3 + l * 64;
    for (int o = threadIdx.x; o < 64 * 64; o += 256) {
        int j = o >> 6, lp = o & 63, hh = lp >> 4, ii = lp & 15;
        float acc = 0.f;
#pragma unroll
        for (int c = 0; c < 16; ++c)
            acc += Wq[j * 64 + hh * 16 + c] * We[ii * 64 + hh * 16 + c];
        Wqm[o] = acc;
    }
    if (threadIdx.x < 64) {
        int hh = threadIdx.x >> 4, ii = threadIdx.x & 15;
        float acc = 0.f;
#pragma unroll
        for (int c = 0; c < 16; ++c)
            acc += bq[hh * 16 + c] * We[ii * 64 + hh * 16 + c];
        bqm[threadIdx.x] = acc;
    }
}

// qn,tq,sn fp32 + kv fp16 (k|v interleaved per node: kv[n][0..63]=k, [64..127]=v).
// Register-blocked 5-in-1 GEMM; k0 loop sequential (unroll 1) -> no spill.
__global__ __launch_bounds__(256) void k_qkvt(const float* __restrict__ h,
                       const float* __restrict__ Wq, const float* __restrict__ bq,
                       const float* __restrict__ Wk, const float* __restrict__ bk,
                       const float* __restrict__ Wv, const float* __restrict__ bv,
                       const float* __restrict__ Wqm, const float* __restrict__ bqm,
                       const float* __restrict__ Ws, const float* __restrict__ bs,
                       float* __restrict__ qn, __half* __restrict__ kv,
                       float* __restrict__ tq, float* __restrict__ sn) {
    __shared__ float sh[64 * 64];
    int base = blockIdx.x * 64;
    for (int i = threadIdx.x; i < 1024; i += 256) {       // 64 rows x 64 cols, float4
        int off = i * 4, row = off >> 6;
        float4 v = (base + row < Nn) ? ((const float4*)(h))[((size_t)base * 64 + off) >> 2]
                                     : make_float4(0.f, 0.f, 0.f, 0.f);
        ((float4*)sh)[i] = v;
    }
    __syncthreads();
    int lane = threadIdx.x & 63, wv = threadIdx.x >> 6;
    float aq[16], ak[16], av[16], at[16], as_[16];
    float _bq = bq[lane], _bk = bk[lane], _bv = bv[lane], _bt = bqm[lane], _bs = bs[lane];
#pragma unroll
    for (int nn = 0; nn < 16; ++nn) {
        aq[nn] = _bq; ak[nn] = _bk; av[nn] = _bv; at[nn] = _bt; as_[nn] = _bs;
    }
#pragma unroll 1
    for (int k0 = 0; k0 < 64; k0 += 4) {
        float wq[4], wk[4], wvv[4], wt[4], ws[4];
#pragma unroll
        for (int j = 0; j < 4; ++j) {
            wq[j] = Wq[(k0 + j) * 64 + lane];
            wk[j] = Wk[(k0 + j) * 64 + lane];
            wvv[j] = Wv[(k0 + j) * 64 + lane];
            wt[j] = Wqm[(k0 + j) * 64 + lane];
            ws[j] = Ws[(k0 + j) * 64 + lane];
        }
#pragma unroll
        for (int nn = 0; nn < 16; ++nn) {
            int row = wv * 16 + nn;
            float4 hv = *(const float4*)&sh[row * 64 + k0];
            aq[nn] = fmaf(hv.x, wq[0], fmaf(hv.y, wq[1], fmaf(hv.z, wq[2], fmaf(hv.w, wq[3], aq[nn]))));
            ak[nn] = fmaf(hv.x, wk[0], fmaf(hv.y, wk[1], fmaf(hv.z, wk[2], fmaf(hv.w, wk[3], ak[nn]))));
            av[nn] = fmaf(hv.x, wvv[0], fmaf(hv.y, wvv[1], fmaf(hv.z, wvv[2], fmaf(hv.w, wvv[3], av[nn]))));
            at[nn] = fmaf(hv.x, wt[0], fmaf(hv.y, wt[1], fmaf(hv.z, wt[2], fmaf(hv.w, wt[3], at[nn]))));
            as_[nn] = fmaf(hv.x, ws[0], fmaf(hv.y, ws[1], fmaf(hv.z, ws[2], fmaf(hv.w, ws[3], as_[nn]))));
        }
    }
#pragma unroll
    for (int nn = 0; nn < 16; ++nn) {
        int n = base + wv * 16 + nn;
        if (n < Nn) {
            size_t o = (size_t)n * 64 + lane;
            qn[o] = aq[nn]; tq[o] = at[nn]; sn[o] = as_[nn];
            kv[(size_t)n * 128 + lane]      = __float2half_rn(ak[nn]);
            kv[(size_t)n * 128 + 64 + lane] = __float2half_rn(av[nn]);
        }
    }
}

// Fully-fused per-layer edge pass: one wave per dst node, online softmax in
// base-2, 4-edge unroll for ILP. k/v/ea gathered in fp16 (halves gather
// bytes; fp16 0.05% rel err keeps alpha error ~5e-3 -> safe vs threshold;
// bf16 would give ~4% attn shift - too risky). SC folded into q,t at load.
template <bool SORTED>
__global__ __launch_bounds__(256) void k_layer(float* __restrict__ h,
                      const float* __restrict__ qn, const __half* __restrict__ kv,
                      const float* __restrict__ tq, const float* __restrict__ sn,
                      const int* __restrict__ row_ptr, const int* __restrict__ src_perm,
                      const int* __restrict__ eperm, const __half* __restrict__ eah,
                      const float* __restrict__ eaf, const float* __restrict__ We) {
    __shared__ float sWe[1024];
    __shared__ float tile[4][64];
    for (int t = threadIdx.x; t < 1024; t += 256) sWe[t] = We[t];
    __syncthreads();
    int lane = threadIdx.x & 63, wv = threadIdx.x >> 6;
    int hh = lane >> 4, cc = lane & 15;
    int n = blockIdx.x * 4 + wv;
    if (n >= Nn) return;
    int beg = row_ptr[n], end = row_ptr[n + 1];
    const float SC = 0.25f * 1.4426950408889634f;  // 1/sqrt(C) * log2(e)
    float q = qn[(size_t)n * 64 + lane] * SC;
    float t = tq[(size_t)n * 64 + lane] * SC;
    float m = -INFINITY, accd = 0.f, accv = 0.f, acce = 0.f;
    int idx = beg;
    for (; idx + 4 <= end; idx += 4) {
        long b0 = (long)src_perm[idx] * 128,     b1 = (long)src_perm[idx + 1] * 128;
        long b2 = (long)src_perm[idx + 2] * 128, b3 = (long)src_perm[idx + 3] * 128;
        float k0 = __half2float(kv[b0 + lane]),      k1 = __half2float(kv[b1 + lane]);
        float k2 = __half2float(kv[b2 + lane]),      k3 = __half2float(kv[b3 + lane]);
        float v0 = __half2float(kv[b0 + 64 + lane]), v1 = __half2float(kv[b1 + 64 + lane]);
        float v2 = __half2float(kv[b2 + 64 + lane]), v3 = __half2float(kv[b3 + 64 + lane]);
        float x0, x1, x2, x3;
        if (SORTED) {
            long o0 = (long)idx * 16;
            x0 = __half2float(eah[o0 + cc]);      x1 = __half2float(eah[o0 + 16 + cc]);
            x2 = __half2float(eah[o0 + 32 + cc]); x3 = __half2float(eah[o0 + 48 + cc]);
        } else {
            x0 = eaf[(long)eperm[idx] * 16 + cc];     x1 = eaf[(long)eperm[idx + 1] * 16 + cc];
            x2 = eaf[(long)eperm[idx + 2] * 16 + cc]; x3 = eaf[(long)eperm[idx + 3] * 16 + cc];
        }
        float a0 = fmaf(q, k0, x0 * t), a1 = fmaf(q, k1, x1 * t);
        float a2 = fmaf(q, k2, x2 * t), a3 = fmaf(q, k3, x3 * t);
        // 4 independent butterfly chains (scheduler interleaves)
        a0 += __shfl_xor(a0, 1, 16); a1 += __shfl_xor(a1, 1, 16);
        a2 += __shfl_xor(a2, 1, 16); a3 += __shfl_xor(a3, 1, 16);
        a0 += __shfl_xor(a0, 2, 16); a1 += __shfl_xor(a1, 2, 16);
        a2 += __shfl_xor(a2, 2, 16); a3 += __shfl_xor(a3, 2, 16);
        a0 += __shfl_xor(a0, 4, 16); a1 += __shfl_xor(a1, 4, 16);
        a2 += __shfl_xor(a2, 4, 16); a3 += __shfl_xor(a3, 4, 16);
        a0 += __shfl_xor(a0, 8, 16); a1 += __shfl_xor(a1, 8, 16);
        a2 += __shfl_xor(a2, 8, 16); a3 += __shfl_xor(a3, 8, 16);
        float mx = fmaxf(fmaxf(a0, a1), fmaxf(a2, a3));
        float nm = fmaxf(m, mx);
        float w = __builtin_exp2f(m - nm);
        float p0 = __builtin_exp2f(a0 - nm), p1 = __builtin_exp2f(a1 - nm);
        float p2 = __builtin_exp2f(a2 - nm), p3 = __builtin_exp2f(a3 - nm);
        accd = fmaf(accd, w, (p0 + p1) + (p2 + p3));
        accv = fmaf(accv, w, fmaf(p0, v0, fmaf(p1, v1, fmaf(p2, v2, p3 * v3))));
        acce = fmaf(acce, w, fmaf(p0, x0, fmaf(p1, x1, fmaf(p2, x2, p3 * x3))));
        m = nm;
    }
    for (; idx < end; ++idx) {
        long b0 = (long)src_perm[idx] * 128;
        float k0 = __half2float(kv[b0 + lane]);
        float v0 = __half2float(kv[b0 + 64 + lane]);
        float x0 = SORTED ? __half2float(eah[(long)idx * 16 + cc])
                          : eaf[(long)eperm[idx] * 16 + cc];
        float a0 = fmaf(q, k0, x0 * t);
        a0 += __shfl_xor(a0, 1, 16);
        a0 += __shfl_xor(a0, 2, 16);
        a0 += __shfl_xor(a0, 4, 16);
        a0 += __shfl_xor(a0, 8, 16);
        float nm = fmaxf(m, a0);
        float w = __builtin_exp2f(m - nm);
        float p0 = __builtin_exp2f(a0 - nm);
        accd = fmaf(accd, w, p0);
        accv = fmaf(accv, w, p0 * v0);
        acce = fmaf(acce, w, p0 * x0);
        m = nm;
    }
    float inv = 1.f / (accd + 1e-16f);
    tile[wv][lane] = acce * inv;  // wave-local LDS round-trip (lockstep, no barrier)
    float re = 0.f;
#pragma unroll
    for (int i = 0; i < 16; ++i)
        re = fmaf(tile[wv][hh * 16 + i], sWe[i * 64 + lane], re);
    size_t o = (size_t)n * 64 + lane;
    float hv = h[o];
    h[o] = hv + fmaxf(fmaf(accv, inv, re + sn[o]), 0.f);
}

// mean-pool per group (batch sorted -> boundaries) + fused MLP head
__global__ void k_pool(const float* __restrict__ h, const int* __restrict__ gstart,
                       const float* __restrict__ W1, const float* __restrict__ b1,
                       const float* __restrict__ W2, const float* __restrict__ b2,
                       float* __restrict__ out) {
    int g = blockIdx.x;
    int lane = threadIdx.x & 63, wv = threadIdx.x >> 6;
    int beg = gstart[g], end = gstart[g + 1];
    __shared__ float red[4][64];
    __shared__ float sp[64];
    __shared__ float sh[32];
    float acc = 0.f;
    for (int n = beg + wv; n < end; n += 4) acc += h[(size_t)n * 64 + lane];
    red[wv][lane] = acc;
    __syncthreads();
    if (threadIdx.x < 64) {
        float c = fmaxf((float)(end - beg), 1.f);
        sp[lane] = (red[0][lane] + red[1][lane] + red[2][lane] + red[3][lane]) / c;
    }
    __syncthreads();
    if (threadIdx.x < 32) {
        int t = threadIdx.x;
        float a = b1[t];
#pragma unroll
        for (int i = 0; i < 64; ++i) a = fmaf(sp[i], W1[i * 32 + t], a);
        sh[t] = fmaxf(a, 0.f) * W2[t];
    }
    __syncthreads();
    if (threadIdx.x == 0) {
        float s = b2[0];
#pragma unroll
        for (int i = 0; i < 32; ++i) s += sh[i];
        out[g] = s;
    }
}

extern "C" void kernel_launch(void* const* d_in, const int* in_sizes, int n_in,
                              void* d_out, int out_size, void* d_ws, size_t ws_size,
                              hipStream_t stream) {
    const float* x   = (const float*)d_in[0];
    const int*   ei  = (const int*)d_in[1];
    const float* ea  = (const float*)d_in[2];
    const int*   bat = (const int*)d_in[3];
    const float* Wn  = (const float*)d_in[4];
    const float* bn  = (const float*)d_in[5];
    const float* Wq  = (const float*)d_in[6];
    const float* bq  = (const float*)d_in[7];
    const float* Wk  = (const float*)d_in[8];
    const float* bk  = (const float*)d_in[9];
    const float* Wv  = (const float*)d_in[10];
    const float* bv  = (const float*)d_in[11];
    const float* We  = (const float*)d_in[12];
    const float* Wsk = (const float*)d_in[13];
    const float* bs  = (const float*)d_in[14];
    const float* W1  = (const float*)d_in[15];
    const float* b1  = (const float*)d_in[16];
    const float* W2  = (const float*)d_in[17];
    const float* b2  = (const float*)d_in[18];
    float* out = (float*)d_out;

    const size_t NH = (size_t)Nn * 64;
    float* h    = (float*)d_ws;
    float* qn   = h + NH;
    float* tq   = h + 2 * NH;
    float* sn   = h + 3 * NH;
    __half* kv  = (__half*)(h + 4 * NH);       // N*128 half == NH floats of space
    float* Wqm3 = h + 5 * NH;                  // 3*4096
    float* bqm3 = Wqm3 + 3 * 4096;             // 3*64
    int* deg       = (int*)(bqm3 + 3 * 64);    // N
    int* row_ptr   = deg + Nn;                 // N+1
    int* cursor    = row_ptr + Nn + 1;         // N
    int* src_perm  = cursor + Nn;              // E
    int* eperm     = src_perm + Ee;            // E
    int* bsum      = eperm + Ee;               // 256
    int* gstart    = bsum + 256;               // G+1
    int* bcur      = gstart + Gg + 1;          // NBUK (padded)
    char* pe = (char*)(bcur + NBUK_PAD);
    __half* ea_h = (__half*)(((uintptr_t)pe + 63) & ~(uintptr_t)63);   // E*16 half
    char* pt = (char*)(ea_h + (size_t)Ee * 16);
    unsigned long long* tmp =
        (unsigned long long*)(((uintptr_t)pt + 15) & ~(uintptr_t)15);  // E u64
    size_t need_eah = ((char*)(ea_h + (size_t)Ee * 16)) - (char*)d_ws;
    size_t need_tmp = ((char*)(tmp + Ee)) - (char*)d_ws;
    // mode 2: bucketed scatter + fused ea permute (fast). mode 1: legacy
    // scatter + easort. mode 0: legacy scatter, fp32 ea gather in k_layer.
    int mode = (ws_size >= need_tmp) ? 2 : (ws_size >= need_eah) ? 1 : 0;

    const int NB = 196;  // ceil(50000/256)
    hipMemsetAsync(deg, 0, Nn * sizeof(int), stream);
    k_hist<<<(Ee + 255) / 256, 256, 0, stream>>>(ei, deg);
    k_scan1<<<NB, 256, 0, stream>>>(deg, row_ptr, bsum);
    k_scan2<<<1, 256, 0, stream>>>(bsum, NB);
    k_scan3<<<(Nn + 256) / 256, 256, 0, stream>>>(row_ptr, bsum);
    hipMemcpyAsync(cursor, row_ptr, Nn * sizeof(int), hipMemcpyDeviceToDevice, stream);
    if (mode == 2) {
        k_binit<<<(NBUK + 255) / 256, 256, 0, stream>>>(row_ptr, bcur);
        k_bucketA<<<(Ee + 255) / 256, 256, 0, stream>>>(ei, bcur, tmp);
        k_bucketB<<<(Ee + 255) / 256, 256, 0, stream>>>(tmp, cursor, src_perm, ea, ea_h);
    } else {
        k_scatter<<<(Ee + 255) / 256, 256, 0, stream>>>(ei, cursor, src_perm, eperm);
        if (mode == 1)
            k_easort<<<((long)Ee * 4 + 255) / 256, 256, 0, stream>>>(ea, eperm, ea_h);
    }
    k_gbound<<<(Nn + 255) / 256, 256, 0, stream>>>(bat, gstart);
    k_wqm3<<<3, 256, 0, stream>>>(Wq, bq, We, Wqm3, bqm3);

    int nodeBlocks = (Nn + 63) / 64;
    k_encode<<<nodeBlocks, 256, 0, stream>>>(x, Wn, bn, h);
    bool sorted = mode >= 1;
    for (int l = 0; l < 3; ++l) {
        k_qkvt<<<nodeBlocks, 256, 0, stream>>>(h, Wq + l * 4096, bq + l * 64,
                                               Wk + l * 4096, bk + l * 64,
                                               Wv + l * 4096, bv + l * 64,
                                               Wqm3 + l * 4096, bqm3 + l * 64,
                                               Wsk + l * 4096, bs + l * 64,
                                               qn, kv, tq, sn);
        if (sorted)
            k_layer<true><<<(Nn + 3) / 4, 256, 0, stream>>>(h, qn, kv, tq, sn,
                    row_ptr, src_perm, eperm, ea_h, ea, We + l * 1024);
        else
            k_layer<false><<<(Nn + 3) / 4, 256, 0, stream>>>(h, qn, kv, tq, sn,
                    row_ptr, src_perm, eperm, ea_h, ea, We + l * 1024);
    }
    k_pool<<<Gg, 256, 0, stream>>>(h, gstart, W1, b1, W2, b2, out);
}

// Round 2
// 909.918 us; speedup vs baseline: 1.2290x; 1.2290x over previous
//
#include <hip/hip_runtime.h>
#include <hip/hip_fp16.h>
#include <stdint.h>

#define Nn 50000
#define Ee 1600000
#define Gg 64

// ---------------- one-time CSR build ----------------
__global__ void k_hist(const int* __restrict__ ei, int* __restrict__ deg) {
    int e = blockIdx.x * blockDim.x + threadIdx.x;
    if (e < Ee) atomicAdd(&deg[ei[Ee + e]], 1);
}

__global__ void k_scan1(const int* __restrict__ deg, int* __restrict__ row_ptr,
                        int* __restrict__ bsum) {
    __shared__ int buf[256];
    int i = blockIdx.x * 256 + threadIdx.x;
    int v = (i < Nn) ? deg[i] : 0;
    buf[threadIdx.x] = v;
    __syncthreads();
    for (int off = 1; off < 256; off <<= 1) {
        int t = (threadIdx.x >= off) ? buf[threadIdx.x - off] : 0;
        __syncthreads();
        buf[threadIdx.x] += t;
        __syncthreads();
    }
    if (i < Nn) row_ptr[i + 1] = buf[threadIdx.x];  // block-local inclusive
    if (threadIdx.x == 255) bsum[blockIdx.x] = buf[255];
}

__global__ void k_scan2(int* __restrict__ bsum, int nb) {
    __shared__ int buf[256];
    int v = (threadIdx.x < nb) ? bsum[threadIdx.x] : 0;
    buf[threadIdx.x] = v;
    __syncthreads();
    for (int off = 1; off < 256; off <<= 1) {
        int t = (threadIdx.x >= off) ? buf[threadIdx.x - off] : 0;
        __syncthreads();
        buf[threadIdx.x] += t;
        __syncthreads();
    }
    if (threadIdx.x < nb) bsum[threadIdx.x] = buf[threadIdx.x];  // inclusive
}

__global__ void k_scan3(int* __restrict__ row_ptr, const int* __restrict__ bsum) {
    int i = blockIdx.x * 256 + threadIdx.x;  // i in [0, Nn]
    if (i > Nn) return;
    if (i == 0) { row_ptr[0] = 0; return; }
    int b = (i - 1) >> 8;
    if (b > 0) row_ptr[i] += bsum[b - 1];
}

// fallback path (workspace too small): original scatter (+ optional easort)
__global__ void k_scatter(const int* __restrict__ ei, int* __restrict__ cursor,
                          int* __restrict__ src_perm, int* __restrict__ eperm) {
    int e = blockIdx.x * blockDim.x + threadIdx.x;
    if (e >= Ee) return;
    int dst = ei[Ee + e];
    int pos = atomicAdd(&cursor[dst], 1);
    src_perm[pos] = ei[e];
    eperm[pos] = e;
}

__global__ void k_easort(const float* __restrict__ ea, const int* __restrict__ eperm,
                         __half* __restrict__ ea_h) {
    long t = (long)blockIdx.x * blockDim.x + threadIdx.x;  // E*4 quarter-rows
    if (t >= (long)Ee * 4) return;
    long idx = t >> 2;
    int e = eperm[idx];
    float4 v = ((const float4*)ea)[(long)e * 4 + (t & 3)];
    __half2 lo = __floats2half2_rn(v.x, v.y);
    __half2 hi = __floats2half2_rn(v.z, v.w);
    ((__half2*)ea_h)[t * 2]     = lo;
    ((__half2*)ea_h)[t * 2 + 1] = hi;
}

// ---- two-pass scatter, atomic-light (main path) ----
// Pass A: per-node cursor (50K addrs -> ~32 atomics/addr, no serialization
// cliff; the 1563-bucket variant had 1024 ops/addr = 160us atomic chain).
// One packed 8B store at the FINAL CSR position (vs two 4B stores before):
// halves partial-line write traffic (145MB -> ~84MB at ~1.1TB/s ECC-RMW).
__global__ void k_scatA(const int* __restrict__ ei, int* __restrict__ cursor,
                        unsigned long long* __restrict__ tmp) {
    int e = blockIdx.x * blockDim.x + threadIdx.x;
    if (e >= Ee) return;
    int src = ei[e];
    int dst = ei[Ee + e];
    int pos = atomicAdd(&cursor[dst], 1);
    tmp[pos] = ((unsigned long long)(unsigned)src << 32) | (unsigned)e;
}

// Pass B: position t IS final -> zero atomics. Coalesced tmp read, coalesced
// src_perm write, random ea row gather (irreducible), fully-coalesced fp16
// ea_h write (wave writes 2KB contiguous). Kills k_easort + eperm entirely.
__global__ void k_scatB(const unsigned long long* __restrict__ tmp,
                        int* __restrict__ src_perm,
                        const float* __restrict__ ea, __half* __restrict__ ea_h) {
    int t = blockIdx.x * blockDim.x + threadIdx.x;
    if (t >= Ee) return;
    unsigned long long p = tmp[t];
    src_perm[t] = (int)(p >> 32);
    int e = (int)(p & 0xFFFFFFFFull);
    const float4* er = (const float4*)(ea + (size_t)e * 16);
    float4 v0 = er[0], v1 = er[1], v2 = er[2], v3 = er[3];
    __half2 h0 = __floats2half2_rn(v0.x, v0.y), h1 = __floats2half2_rn(v0.z, v0.w);
    __half2 h2 = __floats2half2_rn(v1.x, v1.y), h3 = __floats2half2_rn(v1.z, v1.w);
    __half2 h4 = __floats2half2_rn(v2.x, v2.y), h5 = __floats2half2_rn(v2.z, v2.w);
    __half2 h6 = __floats2half2_rn(v3.x, v3.y), h7 = __floats2half2_rn(v3.z, v3.w);
    uint4 a = make_uint4(*(unsigned*)&h0, *(unsigned*)&h1,
                         *(unsigned*)&h2, *(unsigned*)&h3);
    uint4 b = make_uint4(*(unsigned*)&h4, *(unsigned*)&h5,
                         *(unsigned*)&h6, *(unsigned*)&h7);
    uint4* o = (uint4*)(ea_h + (size_t)t * 16);  // ea_h base 64B-aligned
    o[0] = a;
    o[1] = b;
}

__global__ void k_gbound(const int* __restrict__ batch, int* __restrict__ gstart) {
    int n = blockIdx.x * blockDim.x + threadIdx.x;
    if (n >= Nn) return;
    int b = batch[n];
    if (n == 0) { for (int g = 0; g <= b; ++g) gstart[g] = 0; }
    else { int bp = batch[n - 1]; for (int g = bp + 1; g <= b; ++g) gstart[g] = n; }
    if (n == Nn - 1) { for (int g = b + 1; g <= Gg; ++g) gstart[g] = Nn; }
}

// ---------------- node kernels ----------------
// h = relu(x @ Wn + bn). Register-blocked: x-tile in LDS, Wn chunk in regs.
// k0 loop NOT unrolled (full unroll -> load hoisting -> spill, see R4/R5).
__global__ __launch_bounds__(256) void k_encode(const float* __restrict__ x,
                         const float* __restrict__ Wn,
                         const float* __restrict__ bn, float* __restrict__ h) {
    __shared__ float sx[64 * 32];
    int base = blockIdx.x * 64;
    for (int i = threadIdx.x; i < 512; i += 256) {        // 64 rows x 32 cols, float4
        int off = i * 4, row = off >> 5;
        float4 v = (base + row < Nn) ? ((const float4*)(x))[(base * 32 + off) >> 2]
                                     : make_float4(0.f, 0.f, 0.f, 0.f);
        ((float4*)sx)[i] = v;
    }
    __syncthreads();
    int lane = threadIdx.x & 63, wv = threadIdx.x >> 6;
    float acc[16];
    float b = bn[lane];
#pragma unroll
    for (int nn = 0; nn < 16; ++nn) acc[nn] = b;
#pragma unroll 1
    for (int k0 = 0; k0 < 32; k0 += 4) {
        float w0 = Wn[(k0 + 0) * 64 + lane];
        float w1 = Wn[(k0 + 1) * 64 + lane];
        float w2 = Wn[(k0 + 2) * 64 + lane];
        float w3 = Wn[(k0 + 3) * 64 + lane];
#pragma unroll
        for (int nn = 0; nn < 16; ++nn) {
            int row = wv * 16 + nn;
            float4 hv = *(const float4*)&sx[row * 32 + k0];
            acc[nn] = fmaf(hv.x, w0, fmaf(hv.y, w1, fmaf(hv.z, w2, fmaf(hv.w, w3, acc[nn]))));
        }
    }
#pragma unroll
    for (int nn = 0; nn < 16; ++nn) {
        int n = base + wv * 16 + nn;
        if (n < Nn) h[(size_t)n * 64 + lane] = fmaxf(acc[nn], 0.f);
    }
}

// All 3 layers' Wqm/bqm in one launch (block = layer).
__global__ void k_wqm3(const float* __restrict__ Wq_all, const float* __restrict__ bq_all,
                       const float* __restrict__ We_all, float* __restrict__ Wqm3,
                       float* __restrict__ bqm3) {
    int l = blockIdx.x;
    const float* Wq = Wq_all + l * 4096;
    const float* bq = bq_all + l * 64;
    const float* We = We_all + l * 1024;
    float* Wqm = Wqm3 + l * 4096;
    float* bqm = bqm3 + l * 64;
    for (int o = threadIdx.x; o < 64 * 64; o += 256) {
        int j = o >> 6, lp = o & 63, hh = lp >> 4, ii = lp & 15;
        float acc = 0.f;
#pragma unroll
        for (int c = 0; c < 16; ++c)
            acc += Wq[j * 64 + hh * 16 + c] * We[ii * 64 + hh * 16 + c];
        Wqm[o] = acc;
    }
    if (threadIdx.x < 64) {
        int hh = threadIdx.x >> 4, ii = threadIdx.x & 15;
        float acc = 0.f;
#pragma unroll
        for (int c = 0; c < 16; ++c)
            acc += bq[hh * 16 + c] * We[ii * 64 + hh * 16 + c];
        bqm[threadIdx.x] = acc;
    }
}

// qn,tq,sn fp32 + kv fp16 (k|v interleaved per node: kv[n][0..63]=k, [64..127]=v).
// Register-blocked 5-in-1 GEMM; k0 loop sequential (unroll 1) -> no spill.
__global__ __launch_bounds__(256) void k_qkvt(const float* __restrict__ h,
                       const float* __restrict__ Wq, const float* __restrict__ bq,
                       const float* __restrict__ Wk, const float* __restrict__ bk,
                       const float* __restrict__ Wv, const float* __restrict__ bv,
                       const float* __restrict__ Wqm, const float* __restrict__ bqm,
                       const float* __restrict__ Ws, const float* __restrict__ bs,
                       float* __restrict__ qn, __half* __restrict__ kv,
                       float* __restrict__ tq, float* __restrict__ sn) {
    __shared__ float sh[64 * 64];
    int base = blockIdx.x * 64;
    for (int i = threadIdx.x; i < 1024; i += 256) {       // 64 rows x 64 cols, float4
        int off = i * 4, row = off >> 6;
        float4 v = (base + row < Nn) ? ((const float4*)(h))[((size_t)base * 64 + off) >> 2]
                                     : make_float4(0.f, 0.f, 0.f, 0.f);
        ((float4*)sh)[i] = v;
    }
    __syncthreads();
    int lane = threadIdx.x & 63, wv = threadIdx.x >> 6;
    float aq[16], ak[16], av[16], at[16], as_[16];
    float _bq = bq[lane], _bk = bk[lane], _bv = bv[lane], _bt = bqm[lane], _bs = bs[lane];
#pragma unroll
    for (int nn = 0; nn < 16; ++nn) {
        aq[nn] = _bq; ak[nn] = _bk; av[nn] = _bv; at[nn] = _bt; as_[nn] = _bs;
    }
#pragma unroll 1
    for (int k0 = 0; k0 < 64; k0 += 4) {
        float wq[4], wk[4], wvv[4], wt[4], ws[4];
#pragma unroll
        for (int j = 0; j < 4; ++j) {
            wq[j] = Wq[(k0 + j) * 64 + lane];
            wk[j] = Wk[(k0 + j) * 64 + lane];
            wvv[j] = Wv[(k0 + j) * 64 + lane];
            wt[j] = Wqm[(k0 + j) * 64 + lane];
            ws[j] = Ws[(k0 + j) * 64 + lane];
        }
#pragma unroll
        for (int nn = 0; nn < 16; ++nn) {
            int row = wv * 16 + nn;
            float4 hv = *(const float4*)&sh[row * 64 + k0];
            aq[nn] = fmaf(hv.x, wq[0], fmaf(hv.y, wq[1], fmaf(hv.z, wq[2], fmaf(hv.w, wq[3], aq[nn]))));
            ak[nn] = fmaf(hv.x, wk[0], fmaf(hv.y, wk[1], fmaf(hv.z, wk[2], fmaf(hv.w, wk[3], ak[nn]))));
            av[nn] = fmaf(hv.x, wvv[0], fmaf(hv.y, wvv[1], fmaf(hv.z, wvv[2], fmaf(hv.w, wvv[3], av[nn]))));
            at[nn] = fmaf(hv.x, wt[0], fmaf(hv.y, wt[1], fmaf(hv.z, wt[2], fmaf(hv.w, wt[3], at[nn]))));
            as_[nn] = fmaf(hv.x, ws[0], fmaf(hv.y, ws[1], fmaf(hv.z, ws[2], fmaf(hv.w, ws[3], as_[nn]))));
        }
    }
#pragma unroll
    for (int nn = 0; nn < 16; ++nn) {
        int n = base + wv * 16 + nn;
        if (n < Nn) {
            size_t o = (size_t)n * 64 + lane;
            qn[o] = aq[nn]; tq[o] = at[nn]; sn[o] = as_[nn];
            kv[(size_t)n * 128 + lane]      = __float2half_rn(ak[nn]);
            kv[(size_t)n * 128 + 64 + lane] = __float2half_rn(av[nn]);
        }
    }
}

// Fully-fused per-layer edge pass: one wave per dst node, online softmax in
// base-2, 4-edge unroll for ILP. k/v/ea gathered in fp16 (halves gather
// bytes; fp16 0.05% rel err keeps alpha error ~5e-3 -> safe vs threshold;
// bf16 would give ~4% attn shift - too risky). SC folded into q,t at load.
template <bool SORTED>
__global__ __launch_bounds__(256) void k_layer(float* __restrict__ h,
                      const float* __restrict__ qn, const __half* __restrict__ kv,
                      const float* __restrict__ tq, const float* __restrict__ sn,
                      const int* __restrict__ row_ptr, const int* __restrict__ src_perm,
                      const int* __restrict__ eperm, const __half* __restrict__ eah,
                      const float* __restrict__ eaf, const float* __restrict__ We) {
    __shared__ float sWe[1024];
    __shared__ float tile[4][64];
    for (int t = threadIdx.x; t < 1024; t += 256) sWe[t] = We[t];
    __syncthreads();
    int lane = threadIdx.x & 63, wv = threadIdx.x >> 6;
    int hh = lane >> 4, cc = lane & 15;
    int n = blockIdx.x * 4 + wv;
    if (n >= Nn) return;
    int beg = row_ptr[n], end = row_ptr[n + 1];
    const float SC = 0.25f * 1.4426950408889634f;  // 1/sqrt(C) * log2(e)
    float q = qn[(size_t)n * 64 + lane] * SC;
    float t = tq[(size_t)n * 64 + lane] * SC;
    float m = -INFINITY, accd = 0.f, accv = 0.f, acce = 0.f;
    int idx = beg;
    for (; idx + 4 <= end; idx += 4) {
        long b0 = (long)src_perm[idx] * 128,     b1 = (long)src_perm[idx + 1] * 128;
        long b2 = (long)src_perm[idx + 2] * 128, b3 = (long)src_perm[idx + 3] * 128;
        float k0 = __half2float(kv[b0 + lane]),      k1 = __half2float(kv[b1 + lane]);
        float k2 = __half2float(kv[b2 + lane]),      k3 = __half2float(kv[b3 + lane]);
        float v0 = __half2float(kv[b0 + 64 + lane]), v1 = __half2float(kv[b1 + 64 + lane]);
        float v2 = __half2float(kv[b2 + 64 + lane]), v3 = __half2float(kv[b3 + 64 + lane]);
        float x0, x1, x2, x3;
        if (SORTED) {
            long o0 = (long)idx * 16;
            x0 = __half2float(eah[o0 + cc]);      x1 = __half2float(eah[o0 + 16 + cc]);
            x2 = __half2float(eah[o0 + 32 + cc]); x3 = __half2float(eah[o0 + 48 + cc]);
        } else {
            x0 = eaf[(long)eperm[idx] * 16 + cc];     x1 = eaf[(long)eperm[idx + 1] * 16 + cc];
            x2 = eaf[(long)eperm[idx + 2] * 16 + cc]; x3 = eaf[(long)eperm[idx + 3] * 16 + cc];
        }
        float a0 = fmaf(q, k0, x0 * t), a1 = fmaf(q, k1, x1 * t);
        float a2 = fmaf(q, k2, x2 * t), a3 = fmaf(q, k3, x3 * t);
        // 4 independent butterfly chains (scheduler interleaves)
        a0 += __shfl_xor(a0, 1, 16); a1 += __shfl_xor(a1, 1, 16);
        a2 += __shfl_xor(a2, 1, 16); a3 += __shfl_xor(a3, 1, 16);
        a0 += __shfl_xor(a0, 2, 16); a1 += __shfl_xor(a1, 2, 16);
        a2 += __shfl_xor(a2, 2, 16); a3 += __shfl_xor(a3, 2, 16);
        a0 += __shfl_xor(a0, 4, 16); a1 += __shfl_xor(a1, 4, 16);
        a2 += __shfl_xor(a2, 4, 16); a3 += __shfl_xor(a3, 4, 16);
        a0 += __shfl_xor(a0, 8, 16); a1 += __shfl_xor(a1, 8, 16);
        a2 += __shfl_xor(a2, 8, 16); a3 += __shfl_xor(a3, 8, 16);
        float mx = fmaxf(fmaxf(a0, a1), fmaxf(a2, a3));
        float nm = fmaxf(m, mx);
        float w = __builtin_exp2f(m - nm);
        float p0 = __builtin_exp2f(a0 - nm), p1 = __builtin_exp2f(a1 - nm);
        float p2 = __builtin_exp2f(a2 - nm), p3 = __builtin_exp2f(a3 - nm);
        accd = fmaf(accd, w, (p0 + p1) + (p2 + p3));
        accv = fmaf(accv, w, fmaf(p0, v0, fmaf(p1, v1, fmaf(p2, v2, p3 * v3))));
        acce = fmaf(acce, w, fmaf(p0, x0, fmaf(p1, x1, fmaf(p2, x2, p3 * x3))));
        m = nm;
    }
    for (; idx < end; ++idx) {
        long b0 = (long)src_perm[idx] * 128;
        float k0 = __half2float(kv[b0 + lane]);
        float v0 = __half2float(kv[b0 + 64 + lane]);
        float x0 = SORTED ? __half2float(eah[(long)idx * 16 + cc])
                          : eaf[(long)eperm[idx] * 16 + cc];
        float a0 = fmaf(q, k0, x0 * t);
        a0 += __shfl_xor(a0, 1, 16);
        a0 += __shfl_xor(a0, 2, 16);
        a0 += __shfl_xor(a0, 4, 16);
        a0 += __shfl_xor(a0, 8, 16);
        float nm = fmaxf(m, a0);
        float w = __builtin_exp2f(m - nm);
        float p0 = __builtin_exp2f(a0 - nm);
        accd = fmaf(accd, w, p0);
        accv = fmaf(accv, w, p0 * v0);
        acce = fmaf(acce, w, p0 * x0);
        m = nm;
    }
    float inv = 1.f / (accd + 1e-16f);
    tile[wv][lane] = acce * inv;  // wave-local LDS round-trip (lockstep, no barrier)
    float re = 0.f;
#pragma unroll
    for (int i = 0; i < 16; ++i)
        re = fmaf(tile[wv][hh * 16 + i], sWe[i * 64 + lane], re);
    size_t o = (size_t)n * 64 + lane;
    float hv = h[o];
    h[o] = hv + fmaxf(fmaf(accv, inv, re + sn[o]), 0.f);
}

// mean-pool per group (batch sorted -> boundaries) + fused MLP head
__global__ void k_pool(const float* __restrict__ h, const int* __restrict__ gstart,
                       const float* __restrict__ W1, const float* __restrict__ b1,
                       const float* __restrict__ W2, const float* __restrict__ b2,
                       float* __restrict__ out) {
    int g = blockIdx.x;
    int lane = threadIdx.x & 63, wv = threadIdx.x >> 6;
    int beg = gstart[g], end = gstart[g + 1];
    __shared__ float red[4][64];
    __shared__ float sp[64];
    __shared__ float sh[32];
    float acc = 0.f;
    for (int n = beg + wv; n < end; n += 4) acc += h[(size_t)n * 64 + lane];
    red[wv][lane] = acc;
    __syncthreads();
    if (threadIdx.x < 64) {
        float c = fmaxf((float)(end - beg), 1.f);
        sp[lane] = (red[0][lane] + red[1][lane] + red[2][lane] + red[3][lane]) / c;
    }
    __syncthreads();
    if (threadIdx.x < 32) {
        int t = threadIdx.x;
        float a = b1[t];
#pragma unroll
        for (int i = 0; i < 64; ++i) a = fmaf(sp[i], W1[i * 32 + t], a);
        sh[t] = fmaxf(a, 0.f) * W2[t];
    }
    __syncthreads();
    if (threadIdx.x == 0) {
        float s = b2[0];
#pragma unroll
        for (int i = 0; i < 32; ++i) s += sh[i];
        out[g] = s;
    }
}

extern "C" void kernel_launch(void* const* d_in, const int* in_sizes, int n_in,
                              void* d_out, int out_size, void* d_ws, size_t ws_size,
                              hipStream_t stream) {
    const float* x   = (const float*)d_in[0];
    const int*   ei  = (const int*)d_in[1];
    const float* ea  = (const float*)d_in[2];
    const int*   bat = (const int*)d_in[3];
    const float* Wn  = (const float*)d_in[4];
    const float* bn  = (const float*)d_in[5];
    const float* Wq  = (const float*)d_in[6];
    const float* bq  = (const float*)d_in[7];
    const float* Wk  = (const float*)d_in[8];
    const float* bk  = (const float*)d_in[9];
    const float* Wv  = (const float*)d_in[10];
    const float* bv  = (const float*)d_in[11];
    const float* We  = (const float*)d_in[12];
    const float* Wsk = (const float*)d_in[13];
    const float* bs  = (const float*)d_in[14];
    const float* W1  = (const float*)d_in[15];
    const float* b1  = (const float*)d_in[16];
    const float* W2  = (const float*)d_in[17];
    const float* b2  = (const float*)d_in[18];
    float* out = (float*)d_out;

    const size_t NH = (size_t)Nn * 64;
    float* h    = (float*)d_ws;
    float* qn   = h + NH;
    float* tq   = h + 2 * NH;
    float* sn   = h + 3 * NH;
    __half* kv  = (__half*)(h + 4 * NH);       // N*128 half == NH floats of space
    float* Wqm3 = h + 5 * NH;                  // 3*4096
    float* bqm3 = Wqm3 + 3 * 4096;             // 3*64
    int* deg       = (int*)(bqm3 + 3 * 64);    // N
    int* row_ptr   = deg + Nn;                 // N+1
    int* cursor    = row_ptr + Nn + 1;         // N
    int* src_perm  = cursor + Nn;              // E
    int* eperm     = src_perm + Ee;            // E (legacy fallback only)
    int* bsum      = eperm + Ee;               // 256
    int* gstart    = bsum + 256;               // G+1
    char* pe = (char*)(gstart + Gg + 1);
    __half* ea_h = (__half*)(((uintptr_t)pe + 63) & ~(uintptr_t)63);   // E*16 half
    char* pt = (char*)(ea_h + (size_t)Ee * 16);
    unsigned long long* tmp =
        (unsigned long long*)(((uintptr_t)pt + 15) & ~(uintptr_t)15);  // E u64
    size_t need_eah = ((char*)(ea_h + (size_t)Ee * 16)) - (char*)d_ws;
    size_t need_tmp = ((char*)(tmp + Ee)) - (char*)d_ws;
    // mode 2: two-pass scatter (atomic-light passB, fused ea permute+fp16).
    // mode 1: legacy scatter + easort. mode 0: legacy scatter, fp32 ea gather.
    int mode = (ws_size >= need_tmp) ? 2 : (ws_size >= need_eah) ? 1 : 0;

    const int NB = 196;  // ceil(50000/256)
    hipMemsetAsync(deg, 0, Nn * sizeof(int), stream);
    k_hist<<<(Ee + 255) / 256, 256, 0, stream>>>(ei, deg);
    k_scan1<<<NB, 256, 0, stream>>>(deg, row_ptr, bsum);
    k_scan2<<<1, 256, 0, stream>>>(bsum, NB);
    k_scan3<<<(Nn + 256) / 256, 256, 0, stream>>>(row_ptr, bsum);
    hipMemcpyAsync(cursor, row_ptr, Nn * sizeof(int), hipMemcpyDeviceToDevice, stream);
    if (mode == 2) {
        k_scatA<<<(Ee + 255) / 256, 256, 0, stream>>>(ei, cursor, tmp);
        k_scatB<<<(Ee + 255) / 256, 256, 0, stream>>>(tmp, src_perm, ea, ea_h);
    } else {
        k_scatter<<<(Ee + 255) / 256, 256, 0, stream>>>(ei, cursor, src_perm, eperm);
        if (mode == 1)
            k_easort<<<((long)Ee * 4 + 255) / 256, 256, 0, stream>>>(ea, eperm, ea_h);
    }
    k_gbound<<<(Nn + 255) / 256, 256, 0, stream>>>(bat, gstart);
    k_wqm3<<<3, 256, 0, stream>>>(Wq, bq, We, Wqm3, bqm3);

    int nodeBlocks = (Nn + 63) / 64;
    k_encode<<<nodeBlocks, 256, 0, stream>>>(x, Wn, bn, h);
    bool sorted = mode >= 1;
    for (int l = 0; l < 3; ++l) {
        k_qkvt<<<nodeBlocks, 256, 0, stream>>>(h, Wq + l * 4096, bq + l * 64,
                                               Wk + l * 4096, bk + l * 64,
                                               Wv + l * 4096, bv + l * 64,
                                               Wqm3 + l * 4096, bqm3 + l * 64,
                                               Wsk + l * 4096, bs + l * 64,
                                               qn, kv, tq, sn);
        if (sorted)
            k_layer<true><<<(Nn + 3) / 4, 256, 0, stream>>>(h, qn, kv, tq, sn,
                    row_ptr, src_perm, eperm, ea_h, ea, We + l * 1024);
        else
            k_layer<false><<<(Nn + 3) / 4, 256, 0, stream>>>(h, qn, kv, tq, sn,
                    row_ptr, src_perm, eperm, ea_h, ea, We + l * 1024);
    }
    k_pool<<<Gg, 256, 0, stream>>>(h, gstart, W1, b1, W2, b2, out);
}

// Round 3
// 770.299 us; speedup vs baseline: 1.4518x; 1.1813x over previous
//
#include <hip/hip_runtime.h>
#include <hip/hip_fp16.h>
#include <stdint.h>

#define Nn 50000
#define Ee 1600000
#define Gg 64
#define TB 2048                       // edges per bin-tile
#define NTB ((Ee + TB - 1) / TB)      // 782
#define NBK ((Nn + 255) / 256)        // 196 coarse buckets (256 nodes each)

// ---------------- legacy CSR build (fallback modes only) ----------------
__global__ void k_hist(const int* __restrict__ ei, int* __restrict__ deg) {
    int e = blockIdx.x * blockDim.x + threadIdx.x;
    if (e < Ee) atomicAdd(&deg[ei[Ee + e]], 1);
}

__global__ void k_scan1(const int* __restrict__ deg, int* __restrict__ row_ptr,
                        int* __restrict__ bsum) {
    __shared__ int buf[256];
    int i = blockIdx.x * 256 + threadIdx.x;
    int v = (i < Nn) ? deg[i] : 0;
    buf[threadIdx.x] = v;
    __syncthreads();
    for (int off = 1; off < 256; off <<= 1) {
        int t = (threadIdx.x >= off) ? buf[threadIdx.x - off] : 0;
        __syncthreads();
        buf[threadIdx.x] += t;
        __syncthreads();
    }
    if (i < Nn) row_ptr[i + 1] = buf[threadIdx.x];
    if (threadIdx.x == 255) bsum[blockIdx.x] = buf[255];
}

__global__ void k_scan2(int* __restrict__ bsum, int nb) {
    __shared__ int buf[256];
    int v = (threadIdx.x < nb) ? bsum[threadIdx.x] : 0;
    buf[threadIdx.x] = v;
    __syncthreads();
    for (int off = 1; off < 256; off <<= 1) {
        int t = (threadIdx.x >= off) ? buf[threadIdx.x - off] : 0;
        __syncthreads();
        buf[threadIdx.x] += t;
        __syncthreads();
    }
    if (threadIdx.x < nb) bsum[threadIdx.x] = buf[threadIdx.x];
}

__global__ void k_scan3(int* __restrict__ row_ptr, const int* __restrict__ bsum) {
    int i = blockIdx.x * 256 + threadIdx.x;
    if (i > Nn) return;
    if (i == 0) { row_ptr[0] = 0; return; }
    int b = (i - 1) >> 8;
    if (b > 0) row_ptr[i] += bsum[b - 1];
}

__global__ void k_scatter(const int* __restrict__ ei, int* __restrict__ cursor,
                          int* __restrict__ src_perm, int* __restrict__ eperm) {
    int e = blockIdx.x * blockDim.x + threadIdx.x;
    if (e >= Ee) return;
    int dst = ei[Ee + e];
    int pos = atomicAdd(&cursor[dst], 1);
    src_perm[pos] = ei[e];
    eperm[pos] = e;
}

__global__ void k_easort(const float* __restrict__ ea, const int* __restrict__ eperm,
                         __half* __restrict__ ea_h) {
    long t = (long)blockIdx.x * blockDim.x + threadIdx.x;
    if (t >= (long)Ee * 4) return;
    long idx = t >> 2;
    int e = eperm[idx];
    float4 v = ((const float4*)ea)[(long)e * 4 + (t & 3)];
    __half2 lo = __floats2half2_rn(v.x, v.y);
    __half2 hi = __floats2half2_rn(v.z, v.w);
    ((__half2*)ea_h)[t * 2]     = lo;
    ((__half2*)ea_h)[t * 2 + 1] = hi;
}

// ---------------- zero-global-atomic CSR build (main path) ----------------
// Device atomics retire at ~12 G/s on MI355X (R0/R2: 1.6M atomics == ~134us
// regardless of store count). So: NO per-edge global atomics anywhere.
// Counting sort: block-local LDS histograms -> scanned chunk offsets ->
// deterministic placement. All atomics are LDS-scope.

// per-block 196-bucket histogram of a 2048-edge tile
__global__ __launch_bounds__(256) void k_cnt(const int* __restrict__ ei,
                                             int* __restrict__ table) {
    __shared__ int hist[NBK];
    for (int i = threadIdx.x; i < NBK; i += 256) hist[i] = 0;
    __syncthreads();
    int e0 = blockIdx.x * TB;
    for (int i = threadIdx.x; i < TB; i += 256) {
        int e = e0 + i;
        if (e >= Ee) break;
        atomicAdd(&hist[ei[Ee + e] >> 8], 1);    // LDS atomic
    }
    __syncthreads();
    for (int i = threadIdx.x; i < NBK; i += 256)
        table[i * NTB + blockIdx.x] = hist[i];   // column-major for per-bucket scan
}

// per-bucket scan over the NTB block-chunks: table -> exclusive chunk offsets
// (within bucket); bucket total -> bktsz.
__global__ __launch_bounds__(256) void k_colscan(int* __restrict__ table,
                                                 int* __restrict__ bktsz) {
    __shared__ int buf[1024];                    // NTB=782 <= 1024
    int c = blockIdx.x;
    for (int k = 0; k < 4; ++k) {
        int i = threadIdx.x + k * 256;
        buf[i] = (i < NTB) ? table[c * NTB + i] : 0;
    }
    __syncthreads();
    for (int off = 1; off < 1024; off <<= 1) {   // Hillis-Steele inclusive
        int v[4];
        for (int k = 0; k < 4; ++k) {
            int i = threadIdx.x + k * 256;
            v[k] = (i >= off) ? buf[i - off] : 0;
        }
        __syncthreads();
        for (int k = 0; k < 4; ++k) buf[threadIdx.x + k * 256] += v[k];
        __syncthreads();
    }
    for (int k = 0; k < 4; ++k) {
        int i = threadIdx.x + k * 256;
        if (i < NTB) table[c * NTB + i] = i ? buf[i - 1] : 0;  // exclusive
    }
    if (threadIdx.x == 0) bktsz[c] = buf[1023];
}

// exclusive scan of 196 bucket sizes -> bucket bases
__global__ __launch_bounds__(256) void k_bktscan(const int* __restrict__ bktsz,
                                                 int* __restrict__ bktbase) {
    __shared__ int buf[256];
    int i = threadIdx.x;
    buf[i] = (i < NBK) ? bktsz[i] : 0;
    __syncthreads();
    for (int off = 1; off < 256; off <<= 1) {
        int v = (i >= off) ? buf[i - off] : 0;
        __syncthreads();
        buf[i] += v;
        __syncthreads();
    }
    if (i == 0) bktbase[0] = 0;
    if (i < NBK) bktbase[i + 1] = buf[i];
}

// re-read edges, LDS-rank within (block,bucket), store packed record at its
// reserved slot. Scattered 8B stores, but zero atomic dependency (R0/R2
// showed scattered stores alone don't rate-limit).
__global__ __launch_bounds__(256) void k_binfill(const int* __restrict__ ei,
                        const int* __restrict__ table, const int* __restrict__ bktbase,
                        unsigned long long* __restrict__ tmp) {
    __shared__ int off_s[NBK];
    __shared__ int cnt_s[NBK];
    for (int i = threadIdx.x; i < NBK; i += 256) {
        off_s[i] = table[i * NTB + blockIdx.x];
        cnt_s[i] = 0;
    }
    __syncthreads();
    int e0 = blockIdx.x * TB;
    for (int i = threadIdx.x; i < TB; i += 256) {
        int e = e0 + i;
        if (e >= Ee) break;
        int src = ei[e];
        int dst = ei[Ee + e];
        int b = dst >> 8;
        int r = atomicAdd(&cnt_s[b], 1);         // LDS atomic
        long pos = (long)bktbase[b] + off_s[b] + r;
        tmp[pos] = ((unsigned long long)(unsigned)dst << 37)
                 | ((unsigned long long)(unsigned)src << 21)
                 | (unsigned long long)(unsigned)e;
    }
}

// one block per bucket: LDS node-counts -> row_ptr (kills k_hist + scans),
// then place records at final per-node CSR positions (writes confined to the
// bucket's ~65KB span -> L2-local, no sector waste).
__global__ __launch_bounds__(256) void k_bktB(const unsigned long long* __restrict__ tmp,
                        const int* __restrict__ bktbase, int* __restrict__ row_ptr,
                        unsigned long long* __restrict__ tmp2) {
    __shared__ int cnt[256];
    __shared__ int sc[256];
    __shared__ int lro[256];
    int b = blockIdx.x, tid = threadIdx.x;
    cnt[tid] = 0;
    __syncthreads();
    int s = bktbase[b], t_end = bktbase[b + 1];
    for (int i = s + tid; i < t_end; i += 256)
        atomicAdd(&cnt[(int)(tmp[i] >> 37) & 255], 1);
    __syncthreads();
    sc[tid] = cnt[tid];
    __syncthreads();
    for (int off = 1; off < 256; off <<= 1) {
        int v = (tid >= off) ? sc[tid - off] : 0;
        __syncthreads();
        sc[tid] += v;
        __syncthreads();
    }
    lro[tid] = tid ? sc[tid - 1] : 0;            // exclusive local row offset
    cnt[tid] = 0;
    int n = b * 256 + tid;
    if (n < Nn) row_ptr[n] = s + lro[tid];
    if (b == NBK - 1 && tid == 0) row_ptr[Nn] = Ee;
    __syncthreads();
    for (int i = s + tid; i < t_end; i += 256) {
        unsigned long long p = tmp[i];
        int dn = (int)(p >> 37) & 255;
        int r = atomicAdd(&cnt[dn], 1);          // LDS atomic
        int pos = s + lro[dn] + r;
        tmp2[pos] = (((p >> 21) & 0xFFFFull) << 32) | (p & 0x1FFFFFull);
    }
}

// position t IS final -> zero atomics. Coalesced tmp2 read, coalesced
// src_perm write, random ea row gather (irreducible), fully-coalesced fp16
// ea_h write (wave writes 2KB contiguous).
__global__ void k_scatB(const unsigned long long* __restrict__ tmp2,
                        int* __restrict__ src_perm,
                        const float* __restrict__ ea, __half* __restrict__ ea_h) {
    int t = blockIdx.x * blockDim.x + threadIdx.x;
    if (t >= Ee) return;
    unsigned long long p = tmp2[t];
    src_perm[t] = (int)(p >> 32);
    int e = (int)(p & 0xFFFFFFFFull);
    const float4* er = (const float4*)(ea + (size_t)e * 16);
    float4 v0 = er[0], v1 = er[1], v2 = er[2], v3 = er[3];
    __half2 h0 = __floats2half2_rn(v0.x, v0.y), h1 = __floats2half2_rn(v0.z, v0.w);
    __half2 h2 = __floats2half2_rn(v1.x, v1.y), h3 = __floats2half2_rn(v1.z, v1.w);
    __half2 h4 = __floats2half2_rn(v2.x, v2.y), h5 = __floats2half2_rn(v2.z, v2.w);
    __half2 h6 = __floats2half2_rn(v3.x, v3.y), h7 = __floats2half2_rn(v3.z, v3.w);
    uint4 a = make_uint4(*(unsigned*)&h0, *(unsigned*)&h1,
                         *(unsigned*)&h2, *(unsigned*)&h3);
    uint4 bb = make_uint4(*(unsigned*)&h4, *(unsigned*)&h5,
                          *(unsigned*)&h6, *(unsigned*)&h7);
    uint4* o = (uint4*)(ea_h + (size_t)t * 16);
    o[0] = a;
    o[1] = bb;
}

__global__ void k_gbound(const int* __restrict__ batch, int* __restrict__ gstart) {
    int n = blockIdx.x * blockDim.x + threadIdx.x;
    if (n >= Nn) return;
    int b = batch[n];
    if (n == 0) { for (int g = 0; g <= b; ++g) gstart[g] = 0; }
    else { int bp = batch[n - 1]; for (int g = bp + 1; g <= b; ++g) gstart[g] = n; }
    if (n == Nn - 1) { for (int g = b + 1; g <= Gg; ++g) gstart[g] = Nn; }
}

// ---------------- node kernels ----------------
__global__ __launch_bounds__(256) void k_encode(const float* __restrict__ x,
                         const float* __restrict__ Wn,
                         const float* __restrict__ bn, float* __restrict__ h) {
    __shared__ float sx[64 * 32];
    int base = blockIdx.x * 64;
    for (int i = threadIdx.x; i < 512; i += 256) {
        int off = i * 4, row = off >> 5;
        float4 v = (base + row < Nn) ? ((const float4*)(x))[(base * 32 + off) >> 2]
                                     : make_float4(0.f, 0.f, 0.f, 0.f);
        ((float4*)sx)[i] = v;
    }
    __syncthreads();
    int lane = threadIdx.x & 63, wv = threadIdx.x >> 6;
    float acc[16];
    float b = bn[lane];
#pragma unroll
    for (int nn = 0; nn < 16; ++nn) acc[nn] = b;
#pragma unroll 1
    for (int k0 = 0; k0 < 32; k0 += 4) {
        float w0 = Wn[(k0 + 0) * 64 + lane];
        float w1 = Wn[(k0 + 1) * 64 + lane];
        float w2 = Wn[(k0 + 2) * 64 + lane];
        float w3 = Wn[(k0 + 3) * 64 + lane];
#pragma unroll
        for (int nn = 0; nn < 16; ++nn) {
            int row = wv * 16 + nn;
            float4 hv = *(const float4*)&sx[row * 32 + k0];
            acc[nn] = fmaf(hv.x, w0, fmaf(hv.y, w1, fmaf(hv.z, w2, fmaf(hv.w, w3, acc[nn]))));
        }
    }
#pragma unroll
    for (int nn = 0; nn < 16; ++nn) {
        int n = base + wv * 16 + nn;
        if (n < Nn) h[(size_t)n * 64 + lane] = fmaxf(acc[nn], 0.f);
    }
}

__global__ void k_wqm3(const float* __restrict__ Wq_all, const float* __restrict__ bq_all,
                       const float* __restrict__ We_all, float* __restrict__ Wqm3,
                       float* __restrict__ bqm3) {
    int l = blockIdx.x;
    const float* Wq = Wq_all + l * 4096;
    const float* bq = bq_all + l * 64;
    const float* We = We_all + l * 1024;
    float* Wqm = Wqm3 + l * 4096;
    float* bqm = bqm3 + l * 64;
    for (int o = threadIdx.x; o < 64 * 64; o += 256) {
        int j = o >> 6, lp = o & 63, hh = lp >> 4, ii = lp & 15;
        float acc = 0.f;
#pragma unroll
        for (int c = 0; c < 16; ++c)
            acc += Wq[j * 64 + hh * 16 + c] * We[ii * 64 + hh * 16 + c];
        Wqm[o] = acc;
    }
    if (threadIdx.x < 64) {
        int hh = threadIdx.x >> 4, ii = threadIdx.x & 15;
        float acc = 0.f;
#pragma unroll
        for (int c = 0; c < 16; ++c)
            acc += bq[hh * 16 + c] * We[ii * 64 + hh * 16 + c];
        bqm[threadIdx.x] = acc;
    }
}

__global__ __launch_bounds__(256) void k_qkvt(const float* __restrict__ h,
                       const float* __restrict__ Wq, const float* __restrict__ bq,
                       const float* __restrict__ Wk, const float* __restrict__ bk,
                       const float* __restrict__ Wv, const float* __restrict__ bv,
                       const float* __restrict__ Wqm, const float* __restrict__ bqm,
                       const float* __restrict__ Ws, const float* __restrict__ bs,
                       float* __restrict__ qn, __half* __restrict__ kv,
                       float* __restrict__ tq, float* __restrict__ sn) {
    __shared__ float sh[64 * 64];
    int base = blockIdx.x * 64;
    for (int i = threadIdx.x; i < 1024; i += 256) {
        int off = i * 4, row = off >> 6;
        float4 v = (base + row < Nn) ? ((const float4*)(h))[((size_t)base * 64 + off) >> 2]
                                     : make_float4(0.f, 0.f, 0.f, 0.f);
        ((float4*)sh)[i] = v;
    }
    __syncthreads();
    int lane = threadIdx.x & 63, wv = threadIdx.x >> 6;
    float aq[16], ak[16], av[16], at[16], as_[16];
    float _bq = bq[lane], _bk = bk[lane], _bv = bv[lane], _bt = bqm[lane], _bs = bs[lane];
#pragma unroll
    for (int nn = 0; nn < 16; ++nn) {
        aq[nn] = _bq; ak[nn] = _bk; av[nn] = _bv; at[nn] = _bt; as_[nn] = _bs;
    }
#pragma unroll 1
    for (int k0 = 0; k0 < 64; k0 += 4) {
        float wq[4], wk[4], wvv[4], wt[4], ws[4];
#pragma unroll
        for (int j = 0; j < 4; ++j) {
            wq[j] = Wq[(k0 + j) * 64 + lane];
            wk[j] = Wk[(k0 + j) * 64 + lane];
            wvv[j] = Wv[(k0 + j) * 64 + lane];
            wt[j] = Wqm[(k0 + j) * 64 + lane];
            ws[j] = Ws[(k0 + j) * 64 + lane];
        }
#pragma unroll
        for (int nn = 0; nn < 16; ++nn) {
            int row = wv * 16 + nn;
            float4 hv = *(const float4*)&sh[row * 64 + k0];
            aq[nn] = fmaf(hv.x, wq[0], fmaf(hv.y, wq[1], fmaf(hv.z, wq[2], fmaf(hv.w, wq[3], aq[nn]))));
            ak[nn] = fmaf(hv.x, wk[0], fmaf(hv.y, wk[1], fmaf(hv.z, wk[2], fmaf(hv.w, wk[3], ak[nn]))));
            av[nn] = fmaf(hv.x, wvv[0], fmaf(hv.y, wvv[1], fmaf(hv.z, wvv[2], fmaf(hv.w, wvv[3], av[nn]))));
            at[nn] = fmaf(hv.x, wt[0], fmaf(hv.y, wt[1], fmaf(hv.z, wt[2], fmaf(hv.w, wt[3], at[nn]))));
            as_[nn] = fmaf(hv.x, ws[0], fmaf(hv.y, ws[1], fmaf(hv.z, ws[2], fmaf(hv.w, ws[3], as_[nn]))));
        }
    }
#pragma unroll
    for (int nn = 0; nn < 16; ++nn) {
        int n = base + wv * 16 + nn;
        if (n < Nn) {
            size_t o = (size_t)n * 64 + lane;
            qn[o] = aq[nn]; tq[o] = at[nn]; sn[o] = as_[nn];
            kv[(size_t)n * 128 + lane]      = __float2half_rn(ak[nn]);
            kv[(size_t)n * 128 + 64 + lane] = __float2half_rn(av[nn]);
        }
    }
}

template <bool SORTED>
__global__ __launch_bounds__(256) void k_layer(float* __restrict__ h,
                      const float* __restrict__ qn, const __half* __restrict__ kv,
                      const float* __restrict__ tq, const float* __restrict__ sn,
                      const int* __restrict__ row_ptr, const int* __restrict__ src_perm,
                      const int* __restrict__ eperm, const __half* __restrict__ eah,
                      const float* __restrict__ eaf, const float* __restrict__ We) {
    __shared__ float sWe[1024];
    __shared__ float tile[4][64];
    for (int t = threadIdx.x; t < 1024; t += 256) sWe[t] = We[t];
    __syncthreads();
    int lane = threadIdx.x & 63, wv = threadIdx.x >> 6;
    int hh = lane >> 4, cc = lane & 15;
    int n = blockIdx.x * 4 + wv;
    if (n >= Nn) return;
    int beg = row_ptr[n], end = row_ptr[n + 1];
    const float SC = 0.25f * 1.4426950408889634f;  // 1/sqrt(C) * log2(e)
    float q = qn[(size_t)n * 64 + lane] * SC;
    float t = tq[(size_t)n * 64 + lane] * SC;
    float m = -INFINITY, accd = 0.f, accv = 0.f, acce = 0.f;
    int idx = beg;
    for (; idx + 4 <= end; idx += 4) {
        long b0 = (long)src_perm[idx] * 128,     b1 = (long)src_perm[idx + 1] * 128;
        long b2 = (long)src_perm[idx + 2] * 128, b3 = (long)src_perm[idx + 3] * 128;
        float k0 = __half2float(kv[b0 + lane]),      k1 = __half2float(kv[b1 + lane]);
        float k2 = __half2float(kv[b2 + lane]),      k3 = __half2float(kv[b3 + lane]);
        float v0 = __half2float(kv[b0 + 64 + lane]), v1 = __half2float(kv[b1 + 64 + lane]);
        float v2 = __half2float(kv[b2 + 64 + lane]), v3 = __half2float(kv[b3 + 64 + lane]);
        float x0, x1, x2, x3;
        if (SORTED) {
            long o0 = (long)idx * 16;
            x0 = __half2float(eah[o0 + cc]);      x1 = __half2float(eah[o0 + 16 + cc]);
            x2 = __half2float(eah[o0 + 32 + cc]); x3 = __half2float(eah[o0 + 48 + cc]);
        } else {
            x0 = eaf[(long)eperm[idx] * 16 + cc];     x1 = eaf[(long)eperm[idx + 1] * 16 + cc];
            x2 = eaf[(long)eperm[idx + 2] * 16 + cc]; x3 = eaf[(long)eperm[idx + 3] * 16 + cc];
        }
        float a0 = fmaf(q, k0, x0 * t), a1 = fmaf(q, k1, x1 * t);
        float a2 = fmaf(q, k2, x2 * t), a3 = fmaf(q, k3, x3 * t);
        a0 += __shfl_xor(a0, 1, 16); a1 += __shfl_xor(a1, 1, 16);
        a2 += __shfl_xor(a2, 1, 16); a3 += __shfl_xor(a3, 1, 16);
        a0 += __shfl_xor(a0, 2, 16); a1 += __shfl_xor(a1, 2, 16);
        a2 += __shfl_xor(a2, 2, 16); a3 += __shfl_xor(a3, 2, 16);
        a0 += __shfl_xor(a0, 4, 16); a1 += __shfl_xor(a1, 4, 16);
        a2 += __shfl_xor(a2, 4, 16); a3 += __shfl_xor(a3, 4, 16);
        a0 += __shfl_xor(a0, 8, 16); a1 += __shfl_xor(a1, 8, 16);
        a2 += __shfl_xor(a2, 8, 16); a3 += __shfl_xor(a3, 8, 16);
        float mx = fmaxf(fmaxf(a0, a1), fmaxf(a2, a3));
        float nm = fmaxf(m, mx);
        float w = __builtin_exp2f(m - nm);
        float p0 = __builtin_exp2f(a0 - nm), p1 = __builtin_exp2f(a1 - nm);
        float p2 = __builtin_exp2f(a2 - nm), p3 = __builtin_exp2f(a3 - nm);
        accd = fmaf(accd, w, (p0 + p1) + (p2 + p3));
        accv = fmaf(accv, w, fmaf(p0, v0, fmaf(p1, v1, fmaf(p2, v2, p3 * v3))));
        acce = fmaf(acce, w, fmaf(p0, x0, fmaf(p1, x1, fmaf(p2, x2, p3 * x3))));
        m = nm;
    }
    for (; idx < end; ++idx) {
        long b0 = (long)src_perm[idx] * 128;
        float k0 = __half2float(kv[b0 + lane]);
        float v0 = __half2float(kv[b0 + 64 + lane]);
        float x0 = SORTED ? __half2float(eah[(long)idx * 16 + cc])
                          : eaf[(long)eperm[idx] * 16 + cc];
        float a0 = fmaf(q, k0, x0 * t);
        a0 += __shfl_xor(a0, 1, 16);
        a0 += __shfl_xor(a0, 2, 16);
        a0 += __shfl_xor(a0, 4, 16);
        a0 += __shfl_xor(a0, 8, 16);
        float nm = fmaxf(m, a0);
        float w = __builtin_exp2f(m - nm);
        float p0 = __builtin_exp2f(a0 - nm);
        accd = fmaf(accd, w, p0);
        accv = fmaf(accv, w, p0 * v0);
        acce = fmaf(acce, w, p0 * x0);
        m = nm;
    }
    float inv = 1.f / (accd + 1e-16f);
    tile[wv][lane] = acce * inv;
    float re = 0.f;
#pragma unroll
    for (int i = 0; i < 16; ++i)
        re = fmaf(tile[wv][hh * 16 + i], sWe[i * 64 + lane], re);
    size_t o = (size_t)n * 64 + lane;
    float hv = h[o];
    h[o] = hv + fmaxf(fmaf(accv, inv, re + sn[o]), 0.f);
}

__global__ void k_pool(const float* __restrict__ h, const int* __restrict__ gstart,
                       const float* __restrict__ W1, const float* __restrict__ b1,
                       const float* __restrict__ W2, const float* __restrict__ b2,
                       float* __restrict__ out) {
    int g = blockIdx.x;
    int lane = threadIdx.x & 63, wv = threadIdx.x >> 6;
    int beg = gstart[g], end = gstart[g + 1];
    __shared__ float red[4][64];
    __shared__ float sp[64];
    __shared__ float sh[32];
    float acc = 0.f;
    for (int n = beg + wv; n < end; n += 4) acc += h[(size_t)n * 64 + lane];
    red[wv][lane] = acc;
    __syncthreads();
    if (threadIdx.x < 64) {
        float c = fmaxf((float)(end - beg), 1.f);
        sp[lane] = (red[0][lane] + red[1][lane] + red[2][lane] + red[3][lane]) / c;
    }
    __syncthreads();
    if (threadIdx.x < 32) {
        int t = threadIdx.x;
        float a = b1[t];
#pragma unroll
        for (int i = 0; i < 64; ++i) a = fmaf(sp[i], W1[i * 32 + t], a);
        sh[t] = fmaxf(a, 0.f) * W2[t];
    }
    __syncthreads();
    if (threadIdx.x == 0) {
        float s = b2[0];
#pragma unroll
        for (int i = 0; i < 32; ++i) s += sh[i];
        out[g] = s;
    }
}

extern "C" void kernel_launch(void* const* d_in, const int* in_sizes, int n_in,
                              void* d_out, int out_size, void* d_ws, size_t ws_size,
                              hipStream_t stream) {
    const float* x   = (const float*)d_in[0];
    const int*   ei  = (const int*)d_in[1];
    const float* ea  = (const float*)d_in[2];
    const int*   bat = (const int*)d_in[3];
    const float* Wn  = (const float*)d_in[4];
    const float* bn  = (const float*)d_in[5];
    const float* Wq  = (const float*)d_in[6];
    const float* bq  = (const float*)d_in[7];
    const float* Wk  = (const float*)d_in[8];
    const float* bk  = (const float*)d_in[9];
    const float* Wv  = (const float*)d_in[10];
    const float* bv  = (const float*)d_in[11];
    const float* We  = (const float*)d_in[12];
    const float* Wsk = (const float*)d_in[13];
    const float* bs  = (const float*)d_in[14];
    const float* W1  = (const float*)d_in[15];
    const float* b1  = (const float*)d_in[16];
    const float* W2  = (const float*)d_in[17];
    const float* b2  = (const float*)d_in[18];
    float* out = (float*)d_out;

    const size_t NH = (size_t)Nn * 64;
    float* h    = (float*)d_ws;
    float* qn   = h + NH;
    float* tq   = h + 2 * NH;
    float* sn   = h + 3 * NH;
    __half* kv  = (__half*)(h + 4 * NH);       // N*128 half == NH floats of space
    float* Wqm3 = h + 5 * NH;                  // 3*4096
    float* bqm3 = Wqm3 + 3 * 4096;             // 3*64
    int* deg       = (int*)(bqm3 + 3 * 64);    // N (legacy)
    int* row_ptr   = deg + Nn;                 // N+1
    int* cursor    = row_ptr + Nn + 1;         // N (legacy)
    int* src_perm  = cursor + Nn;              // E
    int* eperm     = src_perm + Ee;            // E (legacy fallback only)
    int* bsum      = eperm + Ee;               // 256 (legacy)
    int* gstart    = bsum + 256;               // G+1
    char* pe = (char*)(gstart + Gg + 1);
    __half* ea_h = (__half*)(((uintptr_t)pe + 63) & ~(uintptr_t)63);   // E*16 half
    char* pt = (char*)(ea_h + (size_t)Ee * 16);
    unsigned long long* tmp =
        (unsigned long long*)(((uintptr_t)pt + 15) & ~(uintptr_t)15);  // E u64
    size_t need_eah = ((char*)(ea_h + (size_t)Ee * 16)) - (char*)d_ws;
    size_t need_tmp = ((char*)(tmp + Ee)) - (char*)d_ws;
    // CSR-build scratch overlaid on qn/tq/sn (dead until k_qkvt, and the
    // CSR build fully completes before k_qkvt in stream order):
    unsigned long long* tmp2 = (unsigned long long*)qn;  // E u64 == NH floats exactly
    int* table   = (int*)tq;                             // NBK*NTB ints (~613 KB)
    int* bktsz   = (int*)sn;                             // NBK
    int* bktbase = bktsz + 256;                          // NBK+1
    // mode 2: zero-global-atomic counting-sort CSR build (fast).
    // mode 1: legacy scatter + easort. mode 0: legacy scatter, fp32 ea gather.
    int mode = (ws_size >= need_tmp) ? 2 : (ws_size >= need_eah) ? 1 : 0;

    if (mode == 2) {
        k_cnt<<<NTB, 256, 0, stream>>>(ei, table);
        k_colscan<<<NBK, 256, 0, stream>>>(table, bktsz);
        k_bktscan<<<1, 256, 0, stream>>>(bktsz, bktbase);
        k_binfill<<<NTB, 256, 0, stream>>>(ei, table, bktbase, tmp);
        k_bktB<<<NBK, 256, 0, stream>>>(tmp, bktbase, row_ptr, tmp2);
        k_scatB<<<(Ee + 255) / 256, 256, 0, stream>>>(tmp2, src_perm, ea, ea_h);
    } else {
        const int NB = 196;  // ceil(50000/256)
        hipMemsetAsync(deg, 0, Nn * sizeof(int), stream);
        k_hist<<<(Ee + 255) / 256, 256, 0, stream>>>(ei, deg);
        k_scan1<<<NB, 256, 0, stream>>>(deg, row_ptr, bsum);
        k_scan2<<<1, 256, 0, stream>>>(bsum, NB);
        k_scan3<<<(Nn + 256) / 256, 256, 0, stream>>>(row_ptr, bsum);
        hipMemcpyAsync(cursor, row_ptr, Nn * sizeof(int), hipMemcpyDeviceToDevice, stream);
        k_scatter<<<(Ee + 255) / 256, 256, 0, stream>>>(ei, cursor, src_perm, eperm);
        if (mode == 1)
            k_easort<<<((long)Ee * 4 + 255) / 256, 256, 0, stream>>>(ea, eperm, ea_h);
    }
    k_gbound<<<(Nn + 255) / 256, 256, 0, stream>>>(bat, gstart);
    k_wqm3<<<3, 256, 0, stream>>>(Wq, bq, We, Wqm3, bqm3);

    int nodeBlocks = (Nn + 63) / 64;
    k_encode<<<nodeBlocks, 256, 0, stream>>>(x, Wn, bn, h);
    bool sorted = mode >= 1;
    for (int l = 0; l < 3; ++l) {
        k_qkvt<<<nodeBlocks, 256, 0, stream>>>(h, Wq + l * 4096, bq + l * 64,
                                               Wk + l * 4096, bk + l * 64,
                                               Wv + l * 4096, bv + l * 64,
                                               Wqm3 + l * 4096, bqm3 + l * 64,
                                               Wsk + l * 4096, bs + l * 64,
                                               qn, kv, tq, sn);
        if (sorted)
            k_layer<true><<<(Nn + 3) / 4, 256, 0, stream>>>(h, qn, kv, tq, sn,
                    row_ptr, src_perm, eperm, ea_h, ea, We + l * 1024);
        else
            k_layer<false><<<(Nn + 3) / 4, 256, 0, stream>>>(h, qn, kv, tq, sn,
                    row_ptr, src_perm, eperm, ea_h, ea, We + l * 1024);
    }
    k_pool<<<Gg, 256, 0, stream>>>(h, gstart, W1, b1, W2, b2, out);
}

// Round 4
// 725.169 us; speedup vs baseline: 1.5421x; 1.0622x over previous
//
#include <hip/hip_runtime.h>
#include <hip/hip_fp16.h>
#include <stdint.h>

#define Nn 50000
#define Ee 1600000
#define Gg 64
#define TB 2048                       // edges per bin-tile
#define NTB ((Ee + TB - 1) / TB)      // 782
#define NBK ((Nn + 255) / 256)        // 196 coarse buckets (256 nodes each)

// ---------------- legacy CSR build (fallback modes only) ----------------
__global__ void k_hist(const int* __restrict__ ei, int* __restrict__ deg) {
    int e = blockIdx.x * blockDim.x + threadIdx.x;
    if (e < Ee) atomicAdd(&deg[ei[Ee + e]], 1);
}

__global__ void k_scan1(const int* __restrict__ deg, int* __restrict__ row_ptr,
                        int* __restrict__ bsum) {
    __shared__ int buf[256];
    int i = blockIdx.x * 256 + threadIdx.x;
    int v = (i < Nn) ? deg[i] : 0;
    buf[threadIdx.x] = v;
    __syncthreads();
    for (int off = 1; off < 256; off <<= 1) {
        int t = (threadIdx.x >= off) ? buf[threadIdx.x - off] : 0;
        __syncthreads();
        buf[threadIdx.x] += t;
        __syncthreads();
    }
    if (i < Nn) row_ptr[i + 1] = buf[threadIdx.x];
    if (threadIdx.x == 255) bsum[blockIdx.x] = buf[255];
}

__global__ void k_scan2(int* __restrict__ bsum, int nb) {
    __shared__ int buf[256];
    int v = (threadIdx.x < nb) ? bsum[threadIdx.x] : 0;
    buf[threadIdx.x] = v;
    __syncthreads();
    for (int off = 1; off < 256; off <<= 1) {
        int t = (threadIdx.x >= off) ? buf[threadIdx.x - off] : 0;
        __syncthreads();
        buf[threadIdx.x] += t;
        __syncthreads();
    }
    if (threadIdx.x < nb) bsum[threadIdx.x] = buf[threadIdx.x];
}

__global__ void k_scan3(int* __restrict__ row_ptr, const int* __restrict__ bsum) {
    int i = blockIdx.x * 256 + threadIdx.x;
    if (i > Nn) return;
    if (i == 0) { row_ptr[0] = 0; return; }
    int b = (i - 1) >> 8;
    if (b > 0) row_ptr[i] += bsum[b - 1];
}

__global__ void k_scatter(const int* __restrict__ ei, int* __restrict__ cursor,
                          int* __restrict__ src_perm, int* __restrict__ eperm) {
    int e = blockIdx.x * blockDim.x + threadIdx.x;
    if (e >= Ee) return;
    int dst = ei[Ee + e];
    int pos = atomicAdd(&cursor[dst], 1);
    src_perm[pos] = ei[e];
    eperm[pos] = e;
}

__global__ void k_easort(const float* __restrict__ ea, const int* __restrict__ eperm,
                         __half* __restrict__ ea_h) {
    long t = (long)blockIdx.x * blockDim.x + threadIdx.x;
    if (t >= (long)Ee * 4) return;
    long idx = t >> 2;
    int e = eperm[idx];
    float4 v = ((const float4*)ea)[(long)e * 4 + (t & 3)];
    __half2 lo = __floats2half2_rn(v.x, v.y);
    __half2 hi = __floats2half2_rn(v.z, v.w);
    ((__half2*)ea_h)[t * 2]     = lo;
    ((__half2*)ea_h)[t * 2 + 1] = hi;
}

// ---------------- zero-global-atomic CSR build (main path) ----------------
// Device atomics retire at ~12 G/s on MI355X (R0/R2: 1.6M atomics == ~134us
// regardless of store count). So: NO per-edge global atomics anywhere.
// Counting sort: block-local LDS histograms -> scanned chunk offsets ->
// deterministic placement. All atomics are LDS-scope.

__global__ __launch_bounds__(256) void k_cnt(const int* __restrict__ ei,
                                             int* __restrict__ table) {
    __shared__ int hist[NBK];
    for (int i = threadIdx.x; i < NBK; i += 256) hist[i] = 0;
    __syncthreads();
    int e0 = blockIdx.x * TB;
    for (int i = threadIdx.x; i < TB; i += 256) {
        int e = e0 + i;
        if (e >= Ee) break;
        atomicAdd(&hist[ei[Ee + e] >> 8], 1);    // LDS atomic
    }
    __syncthreads();
    for (int i = threadIdx.x; i < NBK; i += 256)
        table[i * NTB + blockIdx.x] = hist[i];   // column-major for per-bucket scan
}

__global__ __launch_bounds__(256) void k_colscan(int* __restrict__ table,
                                                 int* __restrict__ bktsz) {
    __shared__ int buf[1024];                    // NTB=782 <= 1024
    int c = blockIdx.x;
    for (int k = 0; k < 4; ++k) {
        int i = threadIdx.x + k * 256;
        buf[i] = (i < NTB) ? table[c * NTB + i] : 0;
    }
    __syncthreads();
    for (int off = 1; off < 1024; off <<= 1) {   // Hillis-Steele inclusive
        int v[4];
        for (int k = 0; k < 4; ++k) {
            int i = threadIdx.x + k * 256;
            v[k] = (i >= off) ? buf[i - off] : 0;
        }
        __syncthreads();
        for (int k = 0; k < 4; ++k) buf[threadIdx.x + k * 256] += v[k];
        __syncthreads();
    }
    for (int k = 0; k < 4; ++k) {
        int i = threadIdx.x + k * 256;
        if (i < NTB) table[c * NTB + i] = i ? buf[i - 1] : 0;  // exclusive
    }
    if (threadIdx.x == 0) bktsz[c] = buf[1023];
}

__global__ __launch_bounds__(256) void k_bktscan(const int* __restrict__ bktsz,
                                                 int* __restrict__ bktbase) {
    __shared__ int buf[256];
    int i = threadIdx.x;
    buf[i] = (i < NBK) ? bktsz[i] : 0;
    __syncthreads();
    for (int off = 1; off < 256; off <<= 1) {
        int v = (i >= off) ? buf[i - off] : 0;
        __syncthreads();
        buf[i] += v;
        __syncthreads();
    }
    if (i == 0) bktbase[0] = 0;
    if (i < NBK) bktbase[i + 1] = buf[i];
}

__global__ __launch_bounds__(256) void k_binfill(const int* __restrict__ ei,
                        const int* __restrict__ table, const int* __restrict__ bktbase,
                        unsigned long long* __restrict__ tmp) {
    __shared__ int off_s[NBK];
    __shared__ int cnt_s[NBK];
    for (int i = threadIdx.x; i < NBK; i += 256) {
        off_s[i] = table[i * NTB + blockIdx.x];
        cnt_s[i] = 0;
    }
    __syncthreads();
    int e0 = blockIdx.x * TB;
    for (int i = threadIdx.x; i < TB; i += 256) {
        int e = e0 + i;
        if (e >= Ee) break;
        int src = ei[e];
        int dst = ei[Ee + e];
        int b = dst >> 8;
        int r = atomicAdd(&cnt_s[b], 1);         // LDS atomic
        long pos = (long)bktbase[b] + off_s[b] + r;
        tmp[pos] = ((unsigned long long)(unsigned)dst << 37)
                 | ((unsigned long long)(unsigned)src << 21)
                 | (unsigned long long)(unsigned)e;
    }
}

__global__ __launch_bounds__(256) void k_bktB(const unsigned long long* __restrict__ tmp,
                        const int* __restrict__ bktbase, int* __restrict__ row_ptr,
                        unsigned long long* __restrict__ tmp2) {
    __shared__ int cnt[256];
    __shared__ int sc[256];
    __shared__ int lro[256];
    int b = blockIdx.x, tid = threadIdx.x;
    cnt[tid] = 0;
    __syncthreads();
    int s = bktbase[b], t_end = bktbase[b + 1];
    for (int i = s + tid; i < t_end; i += 256)
        atomicAdd(&cnt[(int)(tmp[i] >> 37) & 255], 1);
    __syncthreads();
    sc[tid] = cnt[tid];
    __syncthreads();
    for (int off = 1; off < 256; off <<= 1) {
        int v = (tid >= off) ? sc[tid - off] : 0;
        __syncthreads();
        sc[tid] += v;
        __syncthreads();
    }
    lro[tid] = tid ? sc[tid - 1] : 0;            // exclusive local row offset
    cnt[tid] = 0;
    int n = b * 256 + tid;
    if (n < Nn) row_ptr[n] = s + lro[tid];
    if (b == NBK - 1 && tid == 0) row_ptr[Nn] = Ee;
    __syncthreads();
    for (int i = s + tid; i < t_end; i += 256) {
        unsigned long long p = tmp[i];
        int dn = (int)(p >> 37) & 255;
        int r = atomicAdd(&cnt[dn], 1);          // LDS atomic
        int pos = s + lro[dn] + r;
        tmp2[pos] = (((p >> 21) & 0xFFFFull) << 32) | (p & 0x1FFFFFull);
    }
}

__global__ void k_scatB(const unsigned long long* __restrict__ tmp2,
                        int* __restrict__ src_perm,
                        const float* __restrict__ ea, __half* __restrict__ ea_h) {
    int t = blockIdx.x * blockDim.x + threadIdx.x;
    if (t >= Ee) return;
    unsigned long long p = tmp2[t];
    src_perm[t] = (int)(p >> 32);
    int e = (int)(p & 0xFFFFFFFFull);
    const float4* er = (const float4*)(ea + (size_t)e * 16);
    float4 v0 = er[0], v1 = er[1], v2 = er[2], v3 = er[3];
    __half2 h0 = __floats2half2_rn(v0.x, v0.y), h1 = __floats2half2_rn(v0.z, v0.w);
    __half2 h2 = __floats2half2_rn(v1.x, v1.y), h3 = __floats2half2_rn(v1.z, v1.w);
    __half2 h4 = __floats2half2_rn(v2.x, v2.y), h5 = __floats2half2_rn(v2.z, v2.w);
    __half2 h6 = __floats2half2_rn(v3.x, v3.y), h7 = __floats2half2_rn(v3.z, v3.w);
    uint4 a = make_uint4(*(unsigned*)&h0, *(unsigned*)&h1,
                         *(unsigned*)&h2, *(unsigned*)&h3);
    uint4 bb = make_uint4(*(unsigned*)&h4, *(unsigned*)&h5,
                          *(unsigned*)&h6, *(unsigned*)&h7);
    uint4* o = (uint4*)(ea_h + (size_t)t * 16);
    o[0] = a;
    o[1] = bb;
}

__global__ void k_gbound(const int* __restrict__ batch, int* __restrict__ gstart) {
    int n = blockIdx.x * blockDim.x + threadIdx.x;
    if (n >= Nn) return;
    int b = batch[n];
    if (n == 0) { for (int g = 0; g <= b; ++g) gstart[g] = 0; }
    else { int bp = batch[n - 1]; for (int g = bp + 1; g <= b; ++g) gstart[g] = n; }
    if (n == Nn - 1) { for (int g = b + 1; g <= Gg; ++g) gstart[g] = Nn; }
}

// ---------------- node kernels ----------------
__global__ __launch_bounds__(256) void k_encode(const float* __restrict__ x,
                         const float* __restrict__ Wn,
                         const float* __restrict__ bn, float* __restrict__ h) {
    __shared__ float sx[64 * 32];
    int base = blockIdx.x * 64;
    for (int i = threadIdx.x; i < 512; i += 256) {
        int off = i * 4, row = off >> 5;
        float4 v = (base + row < Nn) ? ((const float4*)(x))[(base * 32 + off) >> 2]
                                     : make_float4(0.f, 0.f, 0.f, 0.f);
        ((float4*)sx)[i] = v;
    }
    __syncthreads();
    int lane = threadIdx.x & 63, wv = threadIdx.x >> 6;
    float acc[16];
    float b = bn[lane];
#pragma unroll
    for (int nn = 0; nn < 16; ++nn) acc[nn] = b;
#pragma unroll 1
    for (int k0 = 0; k0 < 32; k0 += 4) {
        float w0 = Wn[(k0 + 0) * 64 + lane];
        float w1 = Wn[(k0 + 1) * 64 + lane];
        float w2 = Wn[(k0 + 2) * 64 + lane];
        float w3 = Wn[(k0 + 3) * 64 + lane];
#pragma unroll
        for (int nn = 0; nn < 16; ++nn) {
            int row = wv * 16 + nn;
            float4 hv = *(const float4*)&sx[row * 32 + k0];
            acc[nn] = fmaf(hv.x, w0, fmaf(hv.y, w1, fmaf(hv.z, w2, fmaf(hv.w, w3, acc[nn]))));
        }
    }
#pragma unroll
    for (int nn = 0; nn < 16; ++nn) {
        int n = base + wv * 16 + nn;
        if (n < Nn) h[(size_t)n * 64 + lane] = fmaxf(acc[nn], 0.f);
    }
}

__global__ void k_wqm3(const float* __restrict__ Wq_all, const float* __restrict__ bq_all,
                       const float* __restrict__ We_all, float* __restrict__ Wqm3,
                       float* __restrict__ bqm3) {
    int l = blockIdx.x;
    const float* Wq = Wq_all + l * 4096;
    const float* bq = bq_all + l * 64;
    const float* We = We_all + l * 1024;
    float* Wqm = Wqm3 + l * 4096;
    float* bqm = bqm3 + l * 64;
    for (int o = threadIdx.x; o < 64 * 64; o += 256) {
        int j = o >> 6, lp = o & 63, hh = lp >> 4, ii = lp & 15;
        float acc = 0.f;
#pragma unroll
        for (int c = 0; c < 16; ++c)
            acc += Wq[j * 64 + hh * 16 + c] * We[ii * 64 + hh * 16 + c];
        Wqm[o] = acc;
    }
    if (threadIdx.x < 64) {
        int hh = threadIdx.x >> 4, ii = threadIdx.x & 15;
        float acc = 0.f;
#pragma unroll
        for (int c = 0; c < 16; ++c)
            acc += bq[hh * 16 + c] * We[ii * 64 + hh * 16 + c];
        bqm[threadIdx.x] = acc;
    }
}

__global__ __launch_bounds__(256) void k_qkvt(const float* __restrict__ h,
                       const float* __restrict__ Wq, const float* __restrict__ bq,
                       const float* __restrict__ Wk, const float* __restrict__ bk,
                       const float* __restrict__ Wv, const float* __restrict__ bv,
                       const float* __restrict__ Wqm, const float* __restrict__ bqm,
                       const float* __restrict__ Ws, const float* __restrict__ bs,
                       float* __restrict__ qn, __half* __restrict__ kv,
                       float* __restrict__ tq, float* __restrict__ sn) {
    __shared__ float sh[64 * 64];
    int base = blockIdx.x * 64;
    for (int i = threadIdx.x; i < 1024; i += 256) {
        int off = i * 4, row = off >> 6;
        float4 v = (base + row < Nn) ? ((const float4*)(h))[((size_t)base * 64 + off) >> 2]
                                     : make_float4(0.f, 0.f, 0.f, 0.f);
        ((float4*)sh)[i] = v;
    }
    __syncthreads();
    int lane = threadIdx.x & 63, wv = threadIdx.x >> 6;
    float aq[16], ak[16], av[16], at[16], as_[16];
    float _bq = bq[lane], _bk = bk[lane], _bv = bv[lane], _bt = bqm[lane], _bs = bs[lane];
#pragma unroll
    for (int nn = 0; nn < 16; ++nn) {
        aq[nn] = _bq; ak[nn] = _bk; av[nn] = _bv; at[nn] = _bt; as_[nn] = _bs;
    }
#pragma unroll 1
    for (int k0 = 0; k0 < 64; k0 += 4) {
        float wq[4], wk[4], wvv[4], wt[4], ws[4];
#pragma unroll
        for (int j = 0; j < 4; ++j) {
            wq[j] = Wq[(k0 + j) * 64 + lane];
            wk[j] = Wk[(k0 + j) * 64 + lane];
            wvv[j] = Wv[(k0 + j) * 64 + lane];
            wt[j] = Wqm[(k0 + j) * 64 + lane];
            ws[j] = Ws[(k0 + j) * 64 + lane];
        }
#pragma unroll
        for (int nn = 0; nn < 16; ++nn) {
            int row = wv * 16 + nn;
            float4 hv = *(const float4*)&sh[row * 64 + k0];
            aq[nn] = fmaf(hv.x, wq[0], fmaf(hv.y, wq[1], fmaf(hv.z, wq[2], fmaf(hv.w, wq[3], aq[nn]))));
            ak[nn] = fmaf(hv.x, wk[0], fmaf(hv.y, wk[1], fmaf(hv.z, wk[2], fmaf(hv.w, wk[3], ak[nn]))));
            av[nn] = fmaf(hv.x, wvv[0], fmaf(hv.y, wvv[1], fmaf(hv.z, wvv[2], fmaf(hv.w, wvv[3], av[nn]))));
            at[nn] = fmaf(hv.x, wt[0], fmaf(hv.y, wt[1], fmaf(hv.z, wt[2], fmaf(hv.w, wt[3], at[nn]))));
            as_[nn] = fmaf(hv.x, ws[0], fmaf(hv.y, ws[1], fmaf(hv.z, ws[2], fmaf(hv.w, ws[3], as_[nn]))));
        }
    }
#pragma unroll
    for (int nn = 0; nn < 16; ++nn) {
        int n = base + wv * 16 + nn;
        if (n < Nn) {
            size_t o = (size_t)n * 64 + lane;
            qn[o] = aq[nn]; tq[o] = at[nn]; sn[o] = as_[nn];
            kv[(size_t)n * 128 + lane]      = __float2half_rn(ak[nn]);
            kv[(size_t)n * 128 + 64 + lane] = __float2half_rn(av[nn]);
        }
    }
}

// ---- half2-packed edge pass (main path) ----
// R3 PMC: VALUBusy 80%, HBM 26% -> VALU-issue-bound at ~67 wave-instr/edge.
// Pack channels as half2/float2: 32 sub-lanes cover 64 channels, the wave's
// two 32-lane slots process TWO edges at once. Halves load-issue, addressing,
// shuffle depth (8-lane butterfly), exp2/softmax bookkeeping per edge.
// Slots share the running max (one xor-32 shuffle) so the final slot merge
// is a plain add. Masked -INF alpha handles remainders (no tail loop).
__global__ __launch_bounds__(256) void k_layer2(float* __restrict__ h,
                      const float* __restrict__ qn, const __half* __restrict__ kv,
                      const float* __restrict__ tq, const float* __restrict__ sn,
                      const int* __restrict__ row_ptr, const int* __restrict__ src_perm,
                      const __half* __restrict__ eah, const float* __restrict__ We) {
    __shared__ float sWe[1024];
    __shared__ float tE[4][64];
    __shared__ float tV[4][64];
    for (int t = threadIdx.x; t < 1024; t += 256) sWe[t] = We[t];
    __syncthreads();
    int lane = threadIdx.x & 63, wv = threadIdx.x >> 6;
    int slot = lane >> 5, sl = lane & 31;
    int n = blockIdx.x * 4 + wv;
    if (n >= Nn) return;
    int beg = row_ptr[n], end = row_ptr[n + 1];
    const float SC = 0.25f * 1.4426950408889634f;  // 1/sqrt(C) * log2(e)
    float2 q2 = *(const float2*)&qn[(size_t)n * 64 + 2 * sl];
    float2 t2 = *(const float2*)&tq[(size_t)n * 64 + 2 * sl];
    q2.x *= SC; q2.y *= SC; t2.x *= SC; t2.y *= SC;
    const __half2* kv2 = (const __half2*)kv;
    const __half2* ea2 = (const __half2*)eah;
    float m = -INFINITY, accd = 0.f;
    float2 accv = make_float2(0.f, 0.f), acce = make_float2(0.f, 0.f);
    for (int idx = beg; idx < end; idx += 4) {
        int e0 = idx + slot, e1 = idx + 2 + slot;
        bool ok0 = e0 < end, ok1 = e1 < end;
        int i0 = ok0 ? e0 : beg, i1 = ok1 ? e1 : beg;
        int s0 = src_perm[i0], s1 = src_perm[i1];
        float2 k0 = __half22float2(kv2[s0 * 64 + sl]);
        float2 v0 = __half22float2(kv2[s0 * 64 + 32 + sl]);
        float2 k1 = __half22float2(kv2[s1 * 64 + sl]);
        float2 v1 = __half22float2(kv2[s1 * 64 + 32 + sl]);
        float2 x0 = __half22float2(ea2[(size_t)i0 * 8 + (sl & 7)]);
        float2 x1 = __half22float2(ea2[(size_t)i1 * 8 + (sl & 7)]);
        float a0 = fmaf(q2.x, k0.x, fmaf(q2.y, k0.y, fmaf(t2.x, x0.x, t2.y * x0.y)));
        float a1 = fmaf(q2.x, k1.x, fmaf(q2.y, k1.y, fmaf(t2.x, x1.x, t2.y * x1.y)));
        // head = 16 channels = 8 sub-lanes: 3-step butterfly within groups of 8
        a0 += __shfl_xor(a0, 1, 8); a1 += __shfl_xor(a1, 1, 8);
        a0 += __shfl_xor(a0, 2, 8); a1 += __shfl_xor(a1, 2, 8);
        a0 += __shfl_xor(a0, 4, 8); a1 += __shfl_xor(a1, 4, 8);
        if (!ok0) a0 = -INFINITY;
        if (!ok1) a1 = -INFINITY;
        float b0 = __shfl_xor(a0, 32), b1 = __shfl_xor(a1, 32);  // other slot, same head
        float nm = fmaxf(m, fmaxf(fmaxf(a0, b0), fmaxf(a1, b1)));
        float w = __builtin_exp2f(m - nm);
        float p0 = __builtin_exp2f(a0 - nm), p1 = __builtin_exp2f(a1 - nm);
        accd = fmaf(accd, w, p0 + p1);
        accv.x = fmaf(accv.x, w, fmaf(p0, v0.x, p1 * v1.x));
        accv.y = fmaf(accv.y, w, fmaf(p0, v0.y, p1 * v1.y));
        acce.x = fmaf(acce.x, w, fmaf(p0, x0.x, p1 * x1.x));
        acce.y = fmaf(acce.y, w, fmaf(p0, x0.y, p1 * x1.y));
        m = nm;
    }
    // slots carried identical m -> plain add merges the partial sums exactly
    accd   += __shfl_xor(accd, 32);
    accv.x += __shfl_xor(accv.x, 32);
    accv.y += __shfl_xor(accv.y, 32);
    acce.x += __shfl_xor(acce.x, 32);
    acce.y += __shfl_xor(acce.y, 32);
    float inv = 1.f / (accd + 1e-16f);
    if (slot == 0) {
        // channel pair (2sl,2sl+1): tile index 2sl == 16*(sl>>3)+2*(sl&7)
        ((float2*)tE[wv])[sl] = make_float2(acce.x * inv, acce.y * inv);
        ((float2*)tV[wv])[sl] = make_float2(accv.x * inv, accv.y * inv);
    }
    // wave-lockstep LDS round-trip (same wave wrote it; no barrier)
    int hh = lane >> 4;
    float re = 0.f;
#pragma unroll
    for (int i = 0; i < 16; ++i)
        re = fmaf(tE[wv][hh * 16 + i], sWe[i * 64 + lane], re);
    size_t o = (size_t)n * 64 + lane;
    float hv = h[o];
    h[o] = hv + fmaxf(tV[wv][lane] + re + sn[o], 0.f);
}

// legacy edge pass (fallback mode 0 only: fp32 ea gather via eperm)
template <bool SORTED>
__global__ __launch_bounds__(256) void k_layer(float* __restrict__ h,
                      const float* __restrict__ qn, const __half* __restrict__ kv,
                      const float* __restrict__ tq, const float* __restrict__ sn,
                      const int* __restrict__ row_ptr, const int* __restrict__ src_perm,
                      const int* __restrict__ eperm, const __half* __restrict__ eah,
                      const float* __restrict__ eaf, const float* __restrict__ We) {
    __shared__ float sWe[1024];
    __shared__ float tile[4][64];
    for (int t = threadIdx.x; t < 1024; t += 256) sWe[t] = We[t];
    __syncthreads();
    int lane = threadIdx.x & 63, wv = threadIdx.x >> 6;
    int hh = lane >> 4, cc = lane & 15;
    int n = blockIdx.x * 4 + wv;
    if (n >= Nn) return;
    int beg = row_ptr[n], end = row_ptr[n + 1];
    const float SC = 0.25f * 1.4426950408889634f;
    float q = qn[(size_t)n * 64 + lane] * SC;
    float t = tq[(size_t)n * 64 + lane] * SC;
    float m = -INFINITY, accd = 0.f, accv = 0.f, acce = 0.f;
    int idx = beg;
    for (; idx < end; ++idx) {
        long b0 = (long)src_perm[idx] * 128;
        float k0 = __half2float(kv[b0 + lane]);
        float v0 = __half2float(kv[b0 + 64 + lane]);
        float x0 = SORTED ? __half2float(eah[(long)idx * 16 + cc])
                          : eaf[(long)eperm[idx] * 16 + cc];
        float a0 = fmaf(q, k0, x0 * t);
        a0 += __shfl_xor(a0, 1, 16);
        a0 += __shfl_xor(a0, 2, 16);
        a0 += __shfl_xor(a0, 4, 16);
        a0 += __shfl_xor(a0, 8, 16);
        float nm = fmaxf(m, a0);
        float w = __builtin_exp2f(m - nm);
        float p0 = __builtin_exp2f(a0 - nm);
        accd = fmaf(accd, w, p0);
        accv = fmaf(accv, w, p0 * v0);
        acce = fmaf(acce, w, p0 * x0);
        m = nm;
    }
    float inv = 1.f / (accd + 1e-16f);
    tile[wv][lane] = acce * inv;
    float re = 0.f;
#pragma unroll
    for (int i = 0; i < 16; ++i)
        re = fmaf(tile[wv][hh * 16 + i], sWe[i * 64 + lane], re);
    size_t o = (size_t)n * 64 + lane;
    float hv = h[o];
    h[o] = hv + fmaxf(fmaf(accv, inv, re + sn[o]), 0.f);
}

__global__ void k_pool(const float* __restrict__ h, const int* __restrict__ gstart,
                       const float* __restrict__ W1, const float* __restrict__ b1,
                       const float* __restrict__ W2, const float* __restrict__ b2,
                       float* __restrict__ out) {
    int g = blockIdx.x;
    int lane = threadIdx.x & 63, wv = threadIdx.x >> 6;
    int beg = gstart[g], end = gstart[g + 1];
    __shared__ float red[4][64];
    __shared__ float sp[64];
    __shared__ float sh[32];
    float acc = 0.f;
    for (int n = beg + wv; n < end; n += 4) acc += h[(size_t)n * 64 + lane];
    red[wv][lane] = acc;
    __syncthreads();
    if (threadIdx.x < 64) {
        float c = fmaxf((float)(end - beg), 1.f);
        sp[lane] = (red[0][lane] + red[1][lane] + red[2][lane] + red[3][lane]) / c;
    }
    __syncthreads();
    if (threadIdx.x < 32) {
        int t = threadIdx.x;
        float a = b1[t];
#pragma unroll
        for (int i = 0; i < 64; ++i) a = fmaf(sp[i], W1[i * 32 + t], a);
        sh[t] = fmaxf(a, 0.f) * W2[t];
    }
    __syncthreads();
    if (threadIdx.x == 0) {
        float s = b2[0];
#pragma unroll
        for (int i = 0; i < 32; ++i) s += sh[i];
        out[g] = s;
    }
}

extern "C" void kernel_launch(void* const* d_in, const int* in_sizes, int n_in,
                              void* d_out, int out_size, void* d_ws, size_t ws_size,
                              hipStream_t stream) {
    const float* x   = (const float*)d_in[0];
    const int*   ei  = (const int*)d_in[1];
    const float* ea  = (const float*)d_in[2];
    const int*   bat = (const int*)d_in[3];
    const float* Wn  = (const float*)d_in[4];
    const float* bn  = (const float*)d_in[5];
    const float* Wq  = (const float*)d_in[6];
    const float* bq  = (const float*)d_in[7];
    const float* Wk  = (const float*)d_in[8];
    const float* bk  = (const float*)d_in[9];
    const float* Wv  = (const float*)d_in[10];
    const float* bv  = (const float*)d_in[11];
    const float* We  = (const float*)d_in[12];
    const float* Wsk = (const float*)d_in[13];
    const float* bs  = (const float*)d_in[14];
    const float* W1  = (const float*)d_in[15];
    const float* b1  = (const float*)d_in[16];
    const float* W2  = (const float*)d_in[17];
    const float* b2  = (const float*)d_in[18];
    float* out = (float*)d_out;

    const size_t NH = (size_t)Nn * 64;
    float* h    = (float*)d_ws;
    float* qn   = h + NH;
    float* tq   = h + 2 * NH;
    float* sn   = h + 3 * NH;
    __half* kv  = (__half*)(h + 4 * NH);       // N*128 half == NH floats of space
    float* Wqm3 = h + 5 * NH;                  // 3*4096
    float* bqm3 = Wqm3 + 3 * 4096;             // 3*64
    int* deg       = (int*)(bqm3 + 3 * 64);    // N (legacy)
    int* row_ptr   = deg + Nn;                 // N+1
    int* cursor    = row_ptr + Nn + 1;         // N (legacy)
    int* src_perm  = cursor + Nn;              // E
    int* eperm     = src_perm + Ee;            // E (legacy fallback only)
    int* bsum      = eperm + Ee;               // 256 (legacy)
    int* gstart    = bsum + 256;               // G+1
    char* pe = (char*)(gstart + Gg + 1);
    __half* ea_h = (__half*)(((uintptr_t)pe + 63) & ~(uintptr_t)63);   // E*16 half
    char* pt = (char*)(ea_h + (size_t)Ee * 16);
    unsigned long long* tmp =
        (unsigned long long*)(((uintptr_t)pt + 15) & ~(uintptr_t)15);  // E u64
    size_t need_eah = ((char*)(ea_h + (size_t)Ee * 16)) - (char*)d_ws;
    size_t need_tmp = ((char*)(tmp + Ee)) - (char*)d_ws;
    // CSR-build scratch overlaid on qn/tq/sn (dead until k_qkvt, and the
    // CSR build fully completes before k_qkvt in stream order):
    unsigned long long* tmp2 = (unsigned long long*)qn;  // E u64 == NH floats exactly
    int* table   = (int*)tq;                             // NBK*NTB ints (~613 KB)
    int* bktsz   = (int*)sn;                             // NBK
    int* bktbase = bktsz + 256;                          // NBK+1
    // mode 2: zero-global-atomic counting-sort CSR build (fast).
    // mode 1: legacy scatter + easort. mode 0: legacy scatter, fp32 ea gather.
    int mode = (ws_size >= need_tmp) ? 2 : (ws_size >= need_eah) ? 1 : 0;

    if (mode == 2) {
        k_cnt<<<NTB, 256, 0, stream>>>(ei, table);
        k_colscan<<<NBK, 256, 0, stream>>>(table, bktsz);
        k_bktscan<<<1, 256, 0, stream>>>(bktsz, bktbase);
        k_binfill<<<NTB, 256, 0, stream>>>(ei, table, bktbase, tmp);
        k_bktB<<<NBK, 256, 0, stream>>>(tmp, bktbase, row_ptr, tmp2);
        k_scatB<<<(Ee + 255) / 256, 256, 0, stream>>>(tmp2, src_perm, ea, ea_h);
    } else {
        const int NB = 196;  // ceil(50000/256)
        hipMemsetAsync(deg, 0, Nn * sizeof(int), stream);
        k_hist<<<(Ee + 255) / 256, 256, 0, stream>>>(ei, deg);
        k_scan1<<<NB, 256, 0, stream>>>(deg, row_ptr, bsum);
        k_scan2<<<1, 256, 0, stream>>>(bsum, NB);
        k_scan3<<<(Nn + 256) / 256, 256, 0, stream>>>(row_ptr, bsum);
        hipMemcpyAsync(cursor, row_ptr, Nn * sizeof(int), hipMemcpyDeviceToDevice, stream);
        k_scatter<<<(Ee + 255) / 256, 256, 0, stream>>>(ei, cursor, src_perm, eperm);
        if (mode == 1)
            k_easort<<<((long)Ee * 4 + 255) / 256, 256, 0, stream>>>(ea, eperm, ea_h);
    }
    k_gbound<<<(Nn + 255) / 256, 256, 0, stream>>>(bat, gstart);
    k_wqm3<<<3, 256, 0, stream>>>(Wq, bq, We, Wqm3, bqm3);

    int nodeBlocks = (Nn + 63) / 64;
    k_encode<<<nodeBlocks, 256, 0, stream>>>(x, Wn, bn, h);
    for (int l = 0; l < 3; ++l) {
        k_qkvt<<<nodeBlocks, 256, 0, stream>>>(h, Wq + l * 4096, bq + l * 64,
                                               Wk + l * 4096, bk + l * 64,
                                               Wv + l * 4096, bv + l * 64,
                                               Wqm3 + l * 4096, bqm3 + l * 64,
                                               Wsk + l * 4096, bs + l * 64,
                                               qn, kv, tq, sn);
        if (mode >= 1)
            k_layer2<<<(Nn + 3) / 4, 256, 0, stream>>>(h, qn, kv, tq, sn,
                    row_ptr, src_perm, ea_h, We + l * 1024);
        else
            k_layer<false><<<(Nn + 3) / 4, 256, 0, stream>>>(h, qn, kv, tq, sn,
                    row_ptr, src_perm, eperm, ea_h, ea, We + l * 1024);
    }
    k_pool<<<Gg, 256, 0, stream>>>(h, gstart, W1, b1, W2, b2, out);
}

// Round 5
// 681.412 us; speedup vs baseline: 1.6411x; 1.0642x over previous
//
#include <hip/hip_runtime.h>
#include <hip/hip_fp16.h>
#include <stdint.h>

#define Nn 50000
#define Ee 1600000
#define Gg 64
#define TB 2048                       // edges per bin-tile
#define NTB ((Ee + TB - 1) / TB)      // 782
#define NBK ((Nn + 255) / 256)        // 196 coarse buckets (256 nodes each)

typedef _Float16 f16x2 __attribute__((ext_vector_type(2)));
typedef _Float16 f16x4 __attribute__((ext_vector_type(4)));

__device__ __forceinline__ float fdot2f(f16x2 a, f16x2 b, float c) {
#if __has_builtin(__builtin_amdgcn_fdot2)
    return __builtin_amdgcn_fdot2(a, b, c, false);
#else
    return fmaf((float)a[0], (float)b[0], fmaf((float)a[1], (float)b[1], c));
#endif
}

// ---------------- legacy CSR build (fallback modes only) ----------------
__global__ void k_hist(const int* __restrict__ ei, int* __restrict__ deg) {
    int e = blockIdx.x * blockDim.x + threadIdx.x;
    if (e < Ee) atomicAdd(&deg[ei[Ee + e]], 1);
}

__global__ void k_scan1(const int* __restrict__ deg, int* __restrict__ row_ptr,
                        int* __restrict__ bsum) {
    __shared__ int buf[256];
    int i = blockIdx.x * 256 + threadIdx.x;
    int v = (i < Nn) ? deg[i] : 0;
    buf[threadIdx.x] = v;
    __syncthreads();
    for (int off = 1; off < 256; off <<= 1) {
        int t = (threadIdx.x >= off) ? buf[threadIdx.x - off] : 0;
        __syncthreads();
        buf[threadIdx.x] += t;
        __syncthreads();
    }
    if (i < Nn) row_ptr[i + 1] = buf[threadIdx.x];
    if (threadIdx.x == 255) bsum[blockIdx.x] = buf[255];
}

__global__ void k_scan2(int* __restrict__ bsum, int nb) {
    __shared__ int buf[256];
    int v = (threadIdx.x < nb) ? bsum[threadIdx.x] : 0;
    buf[threadIdx.x] = v;
    __syncthreads();
    for (int off = 1; off < 256; off <<= 1) {
        int t = (threadIdx.x >= off) ? buf[threadIdx.x - off] : 0;
        __syncthreads();
        buf[threadIdx.x] += t;
        __syncthreads();
    }
    if (threadIdx.x < nb) bsum[threadIdx.x] = buf[threadIdx.x];
}

__global__ void k_scan3(int* __restrict__ row_ptr, const int* __restrict__ bsum) {
    int i = blockIdx.x * 256 + threadIdx.x;
    if (i > Nn) return;
    if (i == 0) { row_ptr[0] = 0; return; }
    int b = (i - 1) >> 8;
    if (b > 0) row_ptr[i] += bsum[b - 1];
}

__global__ void k_scatter(const int* __restrict__ ei, int* __restrict__ cursor,
                          int* __restrict__ src_perm, int* __restrict__ eperm) {
    int e = blockIdx.x * blockDim.x + threadIdx.x;
    if (e >= Ee) return;
    int dst = ei[Ee + e];
    int pos = atomicAdd(&cursor[dst], 1);
    src_perm[pos] = ei[e];
    eperm[pos] = e;
}

__global__ void k_easort(const float* __restrict__ ea, const int* __restrict__ eperm,
                         __half* __restrict__ ea_h) {
    long t = (long)blockIdx.x * blockDim.x + threadIdx.x;
    if (t >= (long)Ee * 4) return;
    long idx = t >> 2;
    int e = eperm[idx];
    float4 v = ((const float4*)ea)[(long)e * 4 + (t & 3)];
    __half2 lo = __floats2half2_rn(v.x, v.y);
    __half2 hi = __floats2half2_rn(v.z, v.w);
    ((__half2*)ea_h)[t * 2]     = lo;
    ((__half2*)ea_h)[t * 2 + 1] = hi;
}

// ---------------- zero-global-atomic CSR build (main path) ----------------
// Device atomics retire at ~12 G/s on MI355X (R0/R2: 1.6M atomics == ~134us
// regardless of store count). So: NO per-edge global atomics anywhere.

__global__ __launch_bounds__(256) void k_cnt(const int* __restrict__ ei,
                                             int* __restrict__ table) {
    __shared__ int hist[NBK];
    for (int i = threadIdx.x; i < NBK; i += 256) hist[i] = 0;
    __syncthreads();
    int e0 = blockIdx.x * TB;
    for (int i = threadIdx.x; i < TB; i += 256) {
        int e = e0 + i;
        if (e >= Ee) break;
        atomicAdd(&hist[ei[Ee + e] >> 8], 1);    // LDS atomic
    }
    __syncthreads();
    for (int i = threadIdx.x; i < NBK; i += 256)
        table[i * NTB + blockIdx.x] = hist[i];   // column-major for per-bucket scan
}

__global__ __launch_bounds__(256) void k_colscan(int* __restrict__ table,
                                                 int* __restrict__ bktsz) {
    __shared__ int buf[1024];                    // NTB=782 <= 1024
    int c = blockIdx.x;
    for (int k = 0; k < 4; ++k) {
        int i = threadIdx.x + k * 256;
        buf[i] = (i < NTB) ? table[c * NTB + i] : 0;
    }
    __syncthreads();
    for (int off = 1; off < 1024; off <<= 1) {   // Hillis-Steele inclusive
        int v[4];
        for (int k = 0; k < 4; ++k) {
            int i = threadIdx.x + k * 256;
            v[k] = (i >= off) ? buf[i - off] : 0;
        }
        __syncthreads();
        for (int k = 0; k < 4; ++k) buf[threadIdx.x + k * 256] += v[k];
        __syncthreads();
    }
    for (int k = 0; k < 4; ++k) {
        int i = threadIdx.x + k * 256;
        if (i < NTB) table[c * NTB + i] = i ? buf[i - 1] : 0;  // exclusive
    }
    if (threadIdx.x == 0) bktsz[c] = buf[1023];
}

__global__ __launch_bounds__(256) void k_bktscan(const int* __restrict__ bktsz,
                                                 int* __restrict__ bktbase) {
    __shared__ int buf[256];
    int i = threadIdx.x;
    buf[i] = (i < NBK) ? bktsz[i] : 0;
    __syncthreads();
    for (int off = 1; off < 256; off <<= 1) {
        int v = (i >= off) ? buf[i - off] : 0;
        __syncthreads();
        buf[i] += v;
        __syncthreads();
    }
    if (i == 0) bktbase[0] = 0;
    if (i < NBK) bktbase[i + 1] = buf[i];
}

__global__ __launch_bounds__(256) void k_binfill(const int* __restrict__ ei,
                        const int* __restrict__ table, const int* __restrict__ bktbase,
                        unsigned long long* __restrict__ tmp) {
    __shared__ int off_s[NBK];
    __shared__ int cnt_s[NBK];
    for (int i = threadIdx.x; i < NBK; i += 256) {
        off_s[i] = table[i * NTB + blockIdx.x];
        cnt_s[i] = 0;
    }
    __syncthreads();
    int e0 = blockIdx.x * TB;
    for (int i = threadIdx.x; i < TB; i += 256) {
        int e = e0 + i;
        if (e >= Ee) break;
        int src = ei[e];
        int dst = ei[Ee + e];
        int b = dst >> 8;
        int r = atomicAdd(&cnt_s[b], 1);         // LDS atomic
        long pos = (long)bktbase[b] + off_s[b] + r;
        tmp[pos] = ((unsigned long long)(unsigned)dst << 37)
                 | ((unsigned long long)(unsigned)src << 21)
                 | (unsigned long long)(unsigned)e;
    }
}

__global__ __launch_bounds__(256) void k_bktB(const unsigned long long* __restrict__ tmp,
                        const int* __restrict__ bktbase, int* __restrict__ row_ptr,
                        unsigned long long* __restrict__ tmp2) {
    __shared__ int cnt[256];
    __shared__ int sc[256];
    __shared__ int lro[256];
    int b = blockIdx.x, tid = threadIdx.x;
    cnt[tid] = 0;
    __syncthreads();
    int s = bktbase[b], t_end = bktbase[b + 1];
    for (int i = s + tid; i < t_end; i += 256)
        atomicAdd(&cnt[(int)(tmp[i] >> 37) & 255], 1);
    __syncthreads();
    sc[tid] = cnt[tid];
    __syncthreads();
    for (int off = 1; off < 256; off <<= 1) {
        int v = (tid >= off) ? sc[tid - off] : 0;
        __syncthreads();
        sc[tid] += v;
        __syncthreads();
    }
    lro[tid] = tid ? sc[tid - 1] : 0;            // exclusive local row offset
    cnt[tid] = 0;
    int n = b * 256 + tid;
    if (n < Nn) row_ptr[n] = s + lro[tid];
    if (b == NBK - 1 && tid == 0) row_ptr[Nn] = Ee;
    __syncthreads();
    for (int i = s + tid; i < t_end; i += 256) {
        unsigned long long p = tmp[i];
        int dn = (int)(p >> 37) & 255;
        int r = atomicAdd(&cnt[dn], 1);          // LDS atomic
        int pos = s + lro[dn] + r;
        tmp2[pos] = (((p >> 21) & 0xFFFFull) << 32) | (p & 0x1FFFFFull);
    }
}

__global__ void k_scatB(const unsigned long long* __restrict__ tmp2,
                        int* __restrict__ src_perm,
                        const float* __restrict__ ea, __half* __restrict__ ea_h) {
    int t = blockIdx.x * blockDim.x + threadIdx.x;
    if (t >= Ee) return;
    unsigned long long p = tmp2[t];
    src_perm[t] = (int)(p >> 32);
    int e = (int)(p & 0xFFFFFFFFull);
    const float4* er = (const float4*)(ea + (size_t)e * 16);
    float4 v0 = er[0], v1 = er[1], v2 = er[2], v3 = er[3];
    __half2 h0 = __floats2half2_rn(v0.x, v0.y), h1 = __floats2half2_rn(v0.z, v0.w);
    __half2 h2 = __floats2half2_rn(v1.x, v1.y), h3 = __floats2half2_rn(v1.z, v1.w);
    __half2 h4 = __floats2half2_rn(v2.x, v2.y), h5 = __floats2half2_rn(v2.z, v2.w);
    __half2 h6 = __floats2half2_rn(v3.x, v3.y), h7 = __floats2half2_rn(v3.z, v3.w);
    uint4 a = make_uint4(*(unsigned*)&h0, *(unsigned*)&h1,
                         *(unsigned*)&h2, *(unsigned*)&h3);
    uint4 bb = make_uint4(*(unsigned*)&h4, *(unsigned*)&h5,
                          *(unsigned*)&h6, *(unsigned*)&h7);
    uint4* o = (uint4*)(ea_h + (size_t)t * 16);
    o[0] = a;
    o[1] = bb;
}

__global__ void k_gbound(const int* __restrict__ batch, int* __restrict__ gstart) {
    int n = blockIdx.x * blockDim.x + threadIdx.x;
    if (n >= Nn) return;
    int b = batch[n];
    if (n == 0) { for (int g = 0; g <= b; ++g) gstart[g] = 0; }
    else { int bp = batch[n - 1]; for (int g = bp + 1; g <= b; ++g) gstart[g] = n; }
    if (n == Nn - 1) { for (int g = b + 1; g <= Gg; ++g) gstart[g] = Nn; }
}

// ---------------- node kernels ----------------
__global__ __launch_bounds__(256) void k_encode(const float* __restrict__ x,
                         const float* __restrict__ Wn,
                         const float* __restrict__ bn, float* __restrict__ h) {
    __shared__ float sx[64 * 32];
    int base = blockIdx.x * 64;
    for (int i = threadIdx.x; i < 512; i += 256) {
        int off = i * 4, row = off >> 5;
        float4 v = (base + row < Nn) ? ((const float4*)(x))[(base * 32 + off) >> 2]
                                     : make_float4(0.f, 0.f, 0.f, 0.f);
        ((float4*)sx)[i] = v;
    }
    __syncthreads();
    int lane = threadIdx.x & 63, wv = threadIdx.x >> 6;
    float acc[16];
    float b = bn[lane];
#pragma unroll
    for (int nn = 0; nn < 16; ++nn) acc[nn] = b;
#pragma unroll 1
    for (int k0 = 0; k0 < 32; k0 += 4) {
        float w0 = Wn[(k0 + 0) * 64 + lane];
        float w1 = Wn[(k0 + 1) * 64 + lane];
        float w2 = Wn[(k0 + 2) * 64 + lane];
        float w3 = Wn[(k0 + 3) * 64 + lane];
#pragma unroll
        for (int nn = 0; nn < 16; ++nn) {
            int row = wv * 16 + nn;
            float4 hv = *(const float4*)&sx[row * 32 + k0];
            acc[nn] = fmaf(hv.x, w0, fmaf(hv.y, w1, fmaf(hv.z, w2, fmaf(hv.w, w3, acc[nn]))));
        }
    }
#pragma unroll
    for (int nn = 0; nn < 16; ++nn) {
        int n = base + wv * 16 + nn;
        if (n < Nn) h[(size_t)n * 64 + lane] = fmaxf(acc[nn], 0.f);
    }
}

__global__ void k_wqm3(const float* __restrict__ Wq_all, const float* __restrict__ bq_all,
                       const float* __restrict__ We_all, float* __restrict__ Wqm3,
                       float* __restrict__ bqm3) {
    int l = blockIdx.x;
    const float* Wq = Wq_all + l * 4096;
    const float* bq = bq_all + l * 64;
    const float* We = We_all + l * 1024;
    float* Wqm = Wqm3 + l * 4096;
    float* bqm = bqm3 + l * 64;
    for (int o = threadIdx.x; o < 64 * 64; o += 256) {
        int j = o >> 6, lp = o & 63, hh = lp >> 4, ii = lp & 15;
        float acc = 0.f;
#pragma unroll
        for (int c = 0; c < 16; ++c)
            acc += Wq[j * 64 + hh * 16 + c] * We[ii * 64 + hh * 16 + c];
        Wqm[o] = acc;
    }
    if (threadIdx.x < 64) {
        int hh = threadIdx.x >> 4, ii = threadIdx.x & 15;
        float acc = 0.f;
#pragma unroll
        for (int c = 0; c < 16; ++c)
            acc += bq[hh * 16 + c] * We[ii * 64 + hh * 16 + c];
        bqm[threadIdx.x] = acc;
    }
}

__global__ __launch_bounds__(256) void k_qkvt(const float* __restrict__ h,
                       const float* __restrict__ Wq, const float* __restrict__ bq,
                       const float* __restrict__ Wk, const float* __restrict__ bk,
                       const float* __restrict__ Wv, const float* __restrict__ bv,
                       const float* __restrict__ Wqm, const float* __restrict__ bqm,
                       const float* __restrict__ Ws, const float* __restrict__ bs,
                       float* __restrict__ qn, __half* __restrict__ kv,
                       float* __restrict__ tq, float* __restrict__ sn) {
    __shared__ float sh[64 * 64];
    int base = blockIdx.x * 64;
    for (int i = threadIdx.x; i < 1024; i += 256) {
        int off = i * 4, row = off >> 6;
        float4 v = (base + row < Nn) ? ((const float4*)(h))[((size_t)base * 64 + off) >> 2]
                                     : make_float4(0.f, 0.f, 0.f, 0.f);
        ((float4*)sh)[i] = v;
    }
    __syncthreads();
    int lane = threadIdx.x & 63, wv = threadIdx.x >> 6;
    float aq[16], ak[16], av[16], at[16], as_[16];
    float _bq = bq[lane], _bk = bk[lane], _bv = bv[lane], _bt = bqm[lane], _bs = bs[lane];
#pragma unroll
    for (int nn = 0; nn < 16; ++nn) {
        aq[nn] = _bq; ak[nn] = _bk; av[nn] = _bv; at[nn] = _bt; as_[nn] = _bs;
    }
#pragma unroll 1
    for (int k0 = 0; k0 < 64; k0 += 4) {
        float wq[4], wk[4], wvv[4], wt[4], ws[4];
#pragma unroll
        for (int j = 0; j < 4; ++j) {
            wq[j] = Wq[(k0 + j) * 64 + lane];
            wk[j] = Wk[(k0 + j) * 64 + lane];
            wvv[j] = Wv[(k0 + j) * 64 + lane];
            wt[j] = Wqm[(k0 + j) * 64 + lane];
            ws[j] = Ws[(k0 + j) * 64 + lane];
        }
#pragma unroll
        for (int nn = 0; nn < 16; ++nn) {
            int row = wv * 16 + nn;
            float4 hv = *(const float4*)&sh[row * 64 + k0];
            aq[nn] = fmaf(hv.x, wq[0], fmaf(hv.y, wq[1], fmaf(hv.z, wq[2], fmaf(hv.w, wq[3], aq[nn]))));
            ak[nn] = fmaf(hv.x, wk[0], fmaf(hv.y, wk[1], fmaf(hv.z, wk[2], fmaf(hv.w, wk[3], ak[nn]))));
            av[nn] = fmaf(hv.x, wvv[0], fmaf(hv.y, wvv[1], fmaf(hv.z, wvv[2], fmaf(hv.w, wvv[3], av[nn]))));
            at[nn] = fmaf(hv.x, wt[0], fmaf(hv.y, wt[1], fmaf(hv.z, wt[2], fmaf(hv.w, wt[3], at[nn]))));
            as_[nn] = fmaf(hv.x, ws[0], fmaf(hv.y, ws[1], fmaf(hv.z, ws[2], fmaf(hv.w, ws[3], as_[nn]))));
        }
    }
#pragma unroll
    for (int nn = 0; nn < 16; ++nn) {
        int n = base + wv * 16 + nn;
        if (n < Nn) {
            size_t o = (size_t)n * 64 + lane;
            qn[o] = aq[nn]; tq[o] = at[nn]; sn[o] = as_[nn];
            kv[(size_t)n * 128 + lane]      = __float2half_rn(ak[nn]);
            kv[(size_t)n * 128 + 64 + lane] = __float2half_rn(av[nn]);
        }
    }
}

// ---- fdot2 + fixed-shift-softmax edge pass (main path) ----
// R4 PMC: VALUBusy 77% -> still issue-bound. Cuts: (1) v_dot2_f32_f16 kills
// the k/x fp16->fp32 cvt chain and halves dot fmas (q,t converted to fp16
// once per node; dot-unit products exact, fp32 accumulate). (2) Softmax is
// shift-invariant and alpha*log2e is way below exp2's 127 ceiling -> replace
// online max with a FIXED shift B=24, folded into the dot init (-6/lane x 4
// lanes): no running max, no w-rescale (bare fmaf accumulate), no cross-slot
// sync -> slots fully independent until one final merge. (3) 4 channels/lane,
// 16-lane slots: one VMEM instr gathers k (or v or x) for 4 edges; 2-step
// reduce; 8 edges/iter for gather-latency hiding.
__global__ __launch_bounds__(256) void k_layer4(float* __restrict__ h,
                      const float* __restrict__ qn, const __half* __restrict__ kv,
                      const float* __restrict__ tq, const float* __restrict__ sn,
                      const int* __restrict__ row_ptr, const int* __restrict__ src_perm,
                      const __half* __restrict__ eah, const float* __restrict__ We) {
    __shared__ float sWe[1024];
    __shared__ float tE[4][64];
    __shared__ float tV[4][64];
    for (int t = threadIdx.x; t < 1024; t += 256) sWe[t] = We[t];
    __syncthreads();
    int lane = threadIdx.x & 63, wv = threadIdx.x >> 6;
    int slot = lane >> 4, sl = lane & 15;
    int n = blockIdx.x * 4 + wv;
    if (n >= Nn) return;
    int beg = row_ptr[n], end = row_ptr[n + 1];
    const float SC = 0.25f * 1.4426950408889634f;  // 1/sqrt(C) * log2(e)
    float4 q4 = *(const float4*)&qn[(size_t)n * 64 + 4 * sl];
    float4 t4 = *(const float4*)&tq[(size_t)n * 64 + 4 * sl];
    f16x2 qa = {(_Float16)(q4.x * SC), (_Float16)(q4.y * SC)};
    f16x2 qb = {(_Float16)(q4.z * SC), (_Float16)(q4.w * SC)};
    f16x2 ta = {(_Float16)(t4.x * SC), (_Float16)(t4.y * SC)};
    f16x2 tb = {(_Float16)(t4.z * SC), (_Float16)(t4.w * SC)};
    const int xoff = 4 * (sl & 3);                 // within-head x offset
    float accd = 0.f;
    float4 accv = make_float4(0.f, 0.f, 0.f, 0.f);
    float4 acce = make_float4(0.f, 0.f, 0.f, 0.f);
    for (int idx = beg; idx < end; idx += 8) {
        int e0 = idx + slot, e1 = idx + 4 + slot;
        bool ok0 = e0 < end, ok1 = e1 < end;
        int i0 = ok0 ? e0 : beg, i1 = ok1 ? e1 : beg;
        int s0 = src_perm[i0], s1 = src_perm[i1];
        f16x4 k0 = *(const f16x4*)(kv + (size_t)s0 * 128 + 4 * sl);
        f16x4 v0 = *(const f16x4*)(kv + (size_t)s0 * 128 + 64 + 4 * sl);
        f16x4 k1 = *(const f16x4*)(kv + (size_t)s1 * 128 + 4 * sl);
        f16x4 v1 = *(const f16x4*)(kv + (size_t)s1 * 128 + 64 + 4 * sl);
        f16x4 x0 = *(const f16x4*)(eah + (size_t)i0 * 16 + xoff);
        f16x4 x1 = *(const f16x4*)(eah + (size_t)i1 * 16 + xoff);
        // dot over this lane's 4 channels; init -6 => -24 after 4-lane reduce
        float a0 = fdot2f(qa, __builtin_shufflevector(k0, k0, 0, 1),
                   fdot2f(qb, __builtin_shufflevector(k0, k0, 2, 3),
                   fdot2f(ta, __builtin_shufflevector(x0, x0, 0, 1),
                   fdot2f(tb, __builtin_shufflevector(x0, x0, 2, 3), -6.0f))));
        float a1 = fdot2f(qa, __builtin_shufflevector(k1, k1, 0, 1),
                   fdot2f(qb, __builtin_shufflevector(k1, k1, 2, 3),
                   fdot2f(ta, __builtin_shufflevector(x1, x1, 0, 1),
                   fdot2f(tb, __builtin_shufflevector(x1, x1, 2, 3), -6.0f))));
        a0 += __shfl_xor(a0, 1, 4); a1 += __shfl_xor(a1, 1, 4);
        a0 += __shfl_xor(a0, 2, 4); a1 += __shfl_xor(a1, 2, 4);
        float p0 = ok0 ? __builtin_exp2f(a0) : 0.f;
        float p1 = ok1 ? __builtin_exp2f(a1) : 0.f;
        accd += p0 + p1;
        accv.x = fmaf(p0, (float)v0[0], fmaf(p1, (float)v1[0], accv.x));
        accv.y = fmaf(p0, (float)v0[1], fmaf(p1, (float)v1[1], accv.y));
        accv.z = fmaf(p0, (float)v0[2], fmaf(p1, (float)v1[2], accv.z));
        accv.w = fmaf(p0, (float)v0[3], fmaf(p1, (float)v1[3], accv.w));
        acce.x = fmaf(p0, (float)x0[0], fmaf(p1, (float)x1[0], acce.x));
        acce.y = fmaf(p0, (float)x0[1], fmaf(p1, (float)x1[1], acce.y));
        acce.z = fmaf(p0, (float)x0[2], fmaf(p1, (float)x1[2], acce.z));
        acce.w = fmaf(p0, (float)x0[3], fmaf(p1, (float)x1[3], acce.w));
    }
    // merge the 4 independent slots (shared fixed shift -> plain adds)
    accd   += __shfl_xor(accd, 16);   accd   += __shfl_xor(accd, 32);
    accv.x += __shfl_xor(accv.x, 16); accv.x += __shfl_xor(accv.x, 32);
    accv.y += __shfl_xor(accv.y, 16); accv.y += __shfl_xor(accv.y, 32);
    accv.z += __shfl_xor(accv.z, 16); accv.z += __shfl_xor(accv.z, 32);
    accv.w += __shfl_xor(accv.w, 16); accv.w += __shfl_xor(accv.w, 32);
    acce.x += __shfl_xor(acce.x, 16); acce.x += __shfl_xor(acce.x, 32);
    acce.y += __shfl_xor(acce.y, 16); acce.y += __shfl_xor(acce.y, 32);
    acce.z += __shfl_xor(acce.z, 16); acce.z += __shfl_xor(acce.z, 32);
    acce.w += __shfl_xor(acce.w, 16); acce.w += __shfl_xor(acce.w, 32);
    float inv = 1.f / (accd + 1e-16f);
    if (slot == 0) {
        ((float4*)tE[wv])[sl] = make_float4(acce.x * inv, acce.y * inv,
                                            acce.z * inv, acce.w * inv);
        ((float4*)tV[wv])[sl] = make_float4(accv.x * inv, accv.y * inv,
                                            accv.z * inv, accv.w * inv);
    }
    // wave-lockstep LDS round-trip (same wave wrote it; no barrier)
    int hh = lane >> 4;
    float re = 0.f;
#pragma unroll
    for (int i = 0; i < 16; ++i)
        re = fmaf(tE[wv][hh * 16 + i], sWe[i * 64 + lane], re);
    size_t o = (size_t)n * 64 + lane;
    float hv = h[o];
    h[o] = hv + fmaxf(tV[wv][lane] + re + sn[o], 0.f);
}

// legacy edge pass (fallback mode 0 only: fp32 ea gather via eperm)
template <bool SORTED>
__global__ __launch_bounds__(256) void k_layer(float* __restrict__ h,
                      const float* __restrict__ qn, const __half* __restrict__ kv,
                      const float* __restrict__ tq, const float* __restrict__ sn,
                      const int* __restrict__ row_ptr, const int* __restrict__ src_perm,
                      const int* __restrict__ eperm, const __half* __restrict__ eah,
                      const float* __restrict__ eaf, const float* __restrict__ We) {
    __shared__ float sWe[1024];
    __shared__ float tile[4][64];
    for (int t = threadIdx.x; t < 1024; t += 256) sWe[t] = We[t];
    __syncthreads();
    int lane = threadIdx.x & 63, wv = threadIdx.x >> 6;
    int hh = lane >> 4, cc = lane & 15;
    int n = blockIdx.x * 4 + wv;
    if (n >= Nn) return;
    int beg = row_ptr[n], end = row_ptr[n + 1];
    const float SC = 0.25f * 1.4426950408889634f;
    float q = qn[(size_t)n * 64 + lane] * SC;
    float t = tq[(size_t)n * 64 + lane] * SC;
    float m = -INFINITY, accd = 0.f, accv = 0.f, acce = 0.f;
    int idx = beg;
    for (; idx < end; ++idx) {
        long b0 = (long)src_perm[idx] * 128;
        float k0 = __half2float(kv[b0 + lane]);
        float v0 = __half2float(kv[b0 + 64 + lane]);
        float x0 = SORTED ? __half2float(eah[(long)idx * 16 + cc])
                          : eaf[(long)eperm[idx] * 16 + cc];
        float a0 = fmaf(q, k0, x0 * t);
        a0 += __shfl_xor(a0, 1, 16);
        a0 += __shfl_xor(a0, 2, 16);
        a0 += __shfl_xor(a0, 4, 16);
        a0 += __shfl_xor(a0, 8, 16);
        float nm = fmaxf(m, a0);
        float w = __builtin_exp2f(m - nm);
        float p0 = __builtin_exp2f(a0 - nm);
        accd = fmaf(accd, w, p0);
        accv = fmaf(accv, w, p0 * v0);
        acce = fmaf(acce, w, p0 * x0);
        m = nm;
    }
    float inv = 1.f / (accd + 1e-16f);
    tile[wv][lane] = acce * inv;
    float re = 0.f;
#pragma unroll
    for (int i = 0; i < 16; ++i)
        re = fmaf(tile[wv][hh * 16 + i], sWe[i * 64 + lane], re);
    size_t o = (size_t)n * 64 + lane;
    float hv = h[o];
    h[o] = hv + fmaxf(fmaf(accv, inv, re + sn[o]), 0.f);
}

__global__ void k_pool(const float* __restrict__ h, const int* __restrict__ gstart,
                       const float* __restrict__ W1, const float* __restrict__ b1,
                       const float* __restrict__ W2, const float* __restrict__ b2,
                       float* __restrict__ out) {
    int g = blockIdx.x;
    int lane = threadIdx.x & 63, wv = threadIdx.x >> 6;
    int beg = gstart[g], end = gstart[g + 1];
    __shared__ float red[4][64];
    __shared__ float sp[64];
    __shared__ float sh[32];
    float acc = 0.f;
    for (int n = beg + wv; n < end; n += 4) acc += h[(size_t)n * 64 + lane];
    red[wv][lane] = acc;
    __syncthreads();
    if (threadIdx.x < 64) {
        float c = fmaxf((float)(end - beg), 1.f);
        sp[lane] = (red[0][lane] + red[1][lane] + red[2][lane] + red[3][lane]) / c;
    }
    __syncthreads();
    if (threadIdx.x < 32) {
        int t = threadIdx.x;
        float a = b1[t];
#pragma unroll
        for (int i = 0; i < 64; ++i) a = fmaf(sp[i], W1[i * 32 + t], a);
        sh[t] = fmaxf(a, 0.f) * W2[t];
    }
    __syncthreads();
    if (threadIdx.x == 0) {
        float s = b2[0];
#pragma unroll
        for (int i = 0; i < 32; ++i) s += sh[i];
        out[g] = s;
    }
}

extern "C" void kernel_launch(void* const* d_in, const int* in_sizes, int n_in,
                              void* d_out, int out_size, void* d_ws, size_t ws_size,
                              hipStream_t stream) {
    const float* x   = (const float*)d_in[0];
    const int*   ei  = (const int*)d_in[1];
    const float* ea  = (const float*)d_in[2];
    const int*   bat = (const int*)d_in[3];
    const float* Wn  = (const float*)d_in[4];
    const float* bn  = (const float*)d_in[5];
    const float* Wq  = (const float*)d_in[6];
    const float* bq  = (const float*)d_in[7];
    const float* Wk  = (const float*)d_in[8];
    const float* bk  = (const float*)d_in[9];
    const float* Wv  = (const float*)d_in[10];
    const float* bv  = (const float*)d_in[11];
    const float* We  = (const float*)d_in[12];
    const float* Wsk = (const float*)d_in[13];
    const float* bs  = (const float*)d_in[14];
    const float* W1  = (const float*)d_in[15];
    const float* b1  = (const float*)d_in[16];
    const float* W2  = (const float*)d_in[17];
    const float* b2  = (const float*)d_in[18];
    float* out = (float*)d_out;

    const size_t NH = (size_t)Nn * 64;
    float* h    = (float*)d_ws;
    float* qn   = h + NH;
    float* tq   = h + 2 * NH;
    float* sn   = h + 3 * NH;
    __half* kv  = (__half*)(h + 4 * NH);       // N*128 half == NH floats of space
    float* Wqm3 = h + 5 * NH;                  // 3*4096
    float* bqm3 = Wqm3 + 3 * 4096;             // 3*64
    int* deg       = (int*)(bqm3 + 3 * 64);    // N (legacy)
    int* row_ptr   = deg + Nn;                 // N+1
    int* cursor    = row_ptr + Nn + 1;         // N (legacy)
    int* src_perm  = cursor + Nn;              // E
    int* eperm     = src_perm + Ee;            // E (legacy fallback only)
    int* bsum      = eperm + Ee;               // 256 (legacy)
    int* gstart    = bsum + 256;               // G+1
    char* pe = (char*)(gstart + Gg + 1);
    __half* ea_h = (__half*)(((uintptr_t)pe + 63) & ~(uintptr_t)63);   // E*16 half
    char* pt = (char*)(ea_h + (size_t)Ee * 16);
    unsigned long long* tmp =
        (unsigned long long*)(((uintptr_t)pt + 15) & ~(uintptr_t)15);  // E u64
    size_t need_eah = ((char*)(ea_h + (size_t)Ee * 16)) - (char*)d_ws;
    size_t need_tmp = ((char*)(tmp + Ee)) - (char*)d_ws;
    // CSR-build scratch overlaid on qn/tq/sn (dead until k_qkvt, and the
    // CSR build fully completes before k_qkvt in stream order):
    unsigned long long* tmp2 = (unsigned long long*)qn;  // E u64 == NH floats exactly
    int* table   = (int*)tq;                             // NBK*NTB ints (~613 KB)
    int* bktsz   = (int*)sn;                             // NBK
    int* bktbase = bktsz + 256;                          // NBK+1
    // mode 2: zero-global-atomic counting-sort CSR build (fast).
    // mode 1: legacy scatter + easort. mode 0: legacy scatter, fp32 ea gather.
    int mode = (ws_size >= need_tmp) ? 2 : (ws_size >= need_eah) ? 1 : 0;

    if (mode == 2) {
        k_cnt<<<NTB, 256, 0, stream>>>(ei, table);
        k_colscan<<<NBK, 256, 0, stream>>>(table, bktsz);
        k_bktscan<<<1, 256, 0, stream>>>(bktsz, bktbase);
        k_binfill<<<NTB, 256, 0, stream>>>(ei, table, bktbase, tmp);
        k_bktB<<<NBK, 256, 0, stream>>>(tmp, bktbase, row_ptr, tmp2);
        k_scatB<<<(Ee + 255) / 256, 256, 0, stream>>>(tmp2, src_perm, ea, ea_h);
    } else {
        const int NB = 196;  // ceil(50000/256)
        hipMemsetAsync(deg, 0, Nn * sizeof(int), stream);
        k_hist<<<(Ee + 255) / 256, 256, 0, stream>>>(ei, deg);
        k_scan1<<<NB, 256, 0, stream>>>(deg, row_ptr, bsum);
        k_scan2<<<1, 256, 0, stream>>>(bsum, NB);
        k_scan3<<<(Nn + 256) / 256, 256, 0, stream>>>(row_ptr, bsum);
        hipMemcpyAsync(cursor, row_ptr, Nn * sizeof(int), hipMemcpyDeviceToDevice, stream);
        k_scatter<<<(Ee + 255) / 256, 256, 0, stream>>>(ei, cursor, src_perm, eperm);
        if (mode == 1)
            k_easort<<<((long)Ee * 4 + 255) / 256, 256, 0, stream>>>(ea, eperm, ea_h);
    }
    k_gbound<<<(Nn + 255) / 256, 256, 0, stream>>>(bat, gstart);
    k_wqm3<<<3, 256, 0, stream>>>(Wq, bq, We, Wqm3, bqm3);

    int nodeBlocks = (Nn + 63) / 64;
    k_encode<<<nodeBlocks, 256, 0, stream>>>(x, Wn, bn, h);
    for (int l = 0; l < 3; ++l) {
        k_qkvt<<<nodeBlocks, 256, 0, stream>>>(h, Wq + l * 4096, bq + l * 64,
                                               Wk + l * 4096, bk + l * 64,
                                               Wv + l * 4096, bv + l * 64,
                                               Wqm3 + l * 4096, bqm3 + l * 64,
                                               Wsk + l * 4096, bs + l * 64,
                                               qn, kv, tq, sn);
        if (mode >= 1)
            k_layer4<<<(Nn + 3) / 4, 256, 0, stream>>>(h, qn, kv, tq, sn,
                    row_ptr, src_perm, ea_h, We + l * 1024);
        else
            k_layer<false><<<(Nn + 3) / 4, 256, 0, stream>>>(h, qn, kv, tq, sn,
                    row_ptr, src_perm, eperm, ea_h, ea, We + l * 1024);
    }
    k_pool<<<Gg, 256, 0, stream>>>(h, gstart, W1, b1, W2, b2, out);
}

// Round 6
// 655.566 us; speedup vs baseline: 1.7059x; 1.0394x over previous
//
#include <hip/hip_runtime.h>
#include <hip/hip_fp16.h>
#include <stdint.h>

#define Nn 50000
#define Ee 1600000
#define Gg 64
#define TB 2048                       // edges per bin-tile
#define NTB ((Ee + TB - 1) / TB)      // 782
#define NBK ((Nn + 255) / 256)        // 196 coarse buckets (256 nodes each)

typedef _Float16 f16x2 __attribute__((ext_vector_type(2)));
typedef _Float16 f16x4 __attribute__((ext_vector_type(4)));

__device__ __forceinline__ float fdot2f(f16x2 a, f16x2 b, float c) {
#if __has_builtin(__builtin_amdgcn_fdot2)
    return __builtin_amdgcn_fdot2(a, b, c, false);
#else
    return fmaf((float)a[0], (float)b[0], fmaf((float)a[1], (float)b[1], c));
#endif
}

// ---------------- legacy CSR build (fallback modes only) ----------------
__global__ void k_hist(const int* __restrict__ ei, int* __restrict__ deg) {
    int e = blockIdx.x * blockDim.x + threadIdx.x;
    if (e < Ee) atomicAdd(&deg[ei[Ee + e]], 1);
}

__global__ void k_scan1(const int* __restrict__ deg, int* __restrict__ row_ptr,
                        int* __restrict__ bsum) {
    __shared__ int buf[256];
    int i = blockIdx.x * 256 + threadIdx.x;
    int v = (i < Nn) ? deg[i] : 0;
    buf[threadIdx.x] = v;
    __syncthreads();
    for (int off = 1; off < 256; off <<= 1) {
        int t = (threadIdx.x >= off) ? buf[threadIdx.x - off] : 0;
        __syncthreads();
        buf[threadIdx.x] += t;
        __syncthreads();
    }
    if (i < Nn) row_ptr[i + 1] = buf[threadIdx.x];
    if (threadIdx.x == 255) bsum[blockIdx.x] = buf[255];
}

__global__ void k_scan2(int* __restrict__ bsum, int nb) {
    __shared__ int buf[256];
    int v = (threadIdx.x < nb) ? bsum[threadIdx.x] : 0;
    buf[threadIdx.x] = v;
    __syncthreads();
    for (int off = 1; off < 256; off <<= 1) {
        int t = (threadIdx.x >= off) ? buf[threadIdx.x - off] : 0;
        __syncthreads();
        buf[threadIdx.x] += t;
        __syncthreads();
    }
    if (threadIdx.x < nb) bsum[threadIdx.x] = buf[threadIdx.x];
}

__global__ void k_scan3(int* __restrict__ row_ptr, const int* __restrict__ bsum) {
    int i = blockIdx.x * 256 + threadIdx.x;
    if (i > Nn) return;
    if (i == 0) { row_ptr[0] = 0; return; }
    int b = (i - 1) >> 8;
    if (b > 0) row_ptr[i] += bsum[b - 1];
}

__global__ void k_scatter(const int* __restrict__ ei, int* __restrict__ cursor,
                          int* __restrict__ src_perm, int* __restrict__ eperm) {
    int e = blockIdx.x * blockDim.x + threadIdx.x;
    if (e >= Ee) return;
    int dst = ei[Ee + e];
    int pos = atomicAdd(&cursor[dst], 1);
    src_perm[pos] = ei[e];
    eperm[pos] = e;
}

__global__ void k_easort(const float* __restrict__ ea, const int* __restrict__ eperm,
                         __half* __restrict__ ea_h) {
    long t = (long)blockIdx.x * blockDim.x + threadIdx.x;
    if (t >= (long)Ee * 4) return;
    long idx = t >> 2;
    int e = eperm[idx];
    float4 v = ((const float4*)ea)[(long)e * 4 + (t & 3)];
    __half2 lo = __floats2half2_rn(v.x, v.y);
    __half2 hi = __floats2half2_rn(v.z, v.w);
    ((__half2*)ea_h)[t * 2]     = lo;
    ((__half2*)ea_h)[t * 2 + 1] = hi;
}

// ---------------- zero-global-atomic CSR build (main path) ----------------
// Device atomics retire at ~12 G/s on MI355X (R0/R2: 1.6M atomics == ~134us
// regardless of store count). So: NO per-edge global atomics anywhere.

__global__ __launch_bounds__(256) void k_cnt(const int* __restrict__ ei,
                                             int* __restrict__ table) {
    __shared__ int hist[NBK];
    for (int i = threadIdx.x; i < NBK; i += 256) hist[i] = 0;
    __syncthreads();
    int e0 = blockIdx.x * TB;
    for (int i = threadIdx.x; i < TB; i += 256) {
        int e = e0 + i;
        if (e >= Ee) break;
        atomicAdd(&hist[ei[Ee + e] >> 8], 1);    // LDS atomic
    }
    __syncthreads();
    for (int i = threadIdx.x; i < NBK; i += 256)
        table[i * NTB + blockIdx.x] = hist[i];   // column-major for per-bucket scan
}

__global__ __launch_bounds__(256) void k_colscan(int* __restrict__ table,
                                                 int* __restrict__ bktsz) {
    __shared__ int buf[1024];                    // NTB=782 <= 1024
    int c = blockIdx.x;
    for (int k = 0; k < 4; ++k) {
        int i = threadIdx.x + k * 256;
        buf[i] = (i < NTB) ? table[c * NTB + i] : 0;
    }
    __syncthreads();
    for (int off = 1; off < 1024; off <<= 1) {   // Hillis-Steele inclusive
        int v[4];
        for (int k = 0; k < 4; ++k) {
            int i = threadIdx.x + k * 256;
            v[k] = (i >= off) ? buf[i - off] : 0;
        }
        __syncthreads();
        for (int k = 0; k < 4; ++k) buf[threadIdx.x + k * 256] += v[k];
        __syncthreads();
    }
    for (int k = 0; k < 4; ++k) {
        int i = threadIdx.x + k * 256;
        if (i < NTB) table[c * NTB + i] = i ? buf[i - 1] : 0;  // exclusive
    }
    if (threadIdx.x == 0) bktsz[c] = buf[1023];
}

__global__ __launch_bounds__(256) void k_bktscan(const int* __restrict__ bktsz,
                                                 int* __restrict__ bktbase) {
    __shared__ int buf[256];
    int i = threadIdx.x;
    buf[i] = (i < NBK) ? bktsz[i] : 0;
    __syncthreads();
    for (int off = 1; off < 256; off <<= 1) {
        int v = (i >= off) ? buf[i - off] : 0;
        __syncthreads();
        buf[i] += v;
        __syncthreads();
    }
    if (i == 0) bktbase[0] = 0;
    if (i < NBK) bktbase[i + 1] = buf[i];
}

__global__ __launch_bounds__(256) void k_binfill(const int* __restrict__ ei,
                        const int* __restrict__ table, const int* __restrict__ bktbase,
                        unsigned long long* __restrict__ tmp) {
    __shared__ int off_s[NBK];
    __shared__ int cnt_s[NBK];
    for (int i = threadIdx.x; i < NBK; i += 256) {
        off_s[i] = table[i * NTB + blockIdx.x];
        cnt_s[i] = 0;
    }
    __syncthreads();
    int e0 = blockIdx.x * TB;
    for (int i = threadIdx.x; i < TB; i += 256) {
        int e = e0 + i;
        if (e >= Ee) break;
        int src = ei[e];
        int dst = ei[Ee + e];
        int b = dst >> 8;
        int r = atomicAdd(&cnt_s[b], 1);         // LDS atomic
        long pos = (long)bktbase[b] + off_s[b] + r;
        tmp[pos] = ((unsigned long long)(unsigned)dst << 37)
                 | ((unsigned long long)(unsigned)src << 21)
                 | (unsigned long long)(unsigned)e;
    }
}

__global__ __launch_bounds__(256) void k_bktB(const unsigned long long* __restrict__ tmp,
                        const int* __restrict__ bktbase, int* __restrict__ row_ptr,
                        unsigned long long* __restrict__ tmp2) {
    __shared__ int cnt[256];
    __shared__ int sc[256];
    __shared__ int lro[256];
    int b = blockIdx.x, tid = threadIdx.x;
    cnt[tid] = 0;
    __syncthreads();
    int s = bktbase[b], t_end = bktbase[b + 1];
    for (int i = s + tid; i < t_end; i += 256)
        atomicAdd(&cnt[(int)(tmp[i] >> 37) & 255], 1);
    __syncthreads();
    sc[tid] = cnt[tid];
    __syncthreads();
    for (int off = 1; off < 256; off <<= 1) {
        int v = (tid >= off) ? sc[tid - off] : 0;
        __syncthreads();
        sc[tid] += v;
        __syncthreads();
    }
    lro[tid] = tid ? sc[tid - 1] : 0;            // exclusive local row offset
    cnt[tid] = 0;
    int n = b * 256 + tid;
    if (n < Nn) row_ptr[n] = s + lro[tid];
    if (b == NBK - 1 && tid == 0) row_ptr[Nn] = Ee;
    __syncthreads();
    for (int i = s + tid; i < t_end; i += 256) {
        unsigned long long p = tmp[i];
        int dn = (int)(p >> 37) & 255;
        int r = atomicAdd(&cnt[dn], 1);          // LDS atomic
        int pos = s + lro[dn] + r;
        tmp2[pos] = (((p >> 21) & 0xFFFFull) << 32) | (p & 0x1FFFFFull);
    }
}

__global__ void k_scatB(const unsigned long long* __restrict__ tmp2,
                        int* __restrict__ src_perm,
                        const float* __restrict__ ea, __half* __restrict__ ea_h) {
    int t = blockIdx.x * blockDim.x + threadIdx.x;
    if (t >= Ee) return;
    unsigned long long p = tmp2[t];
    src_perm[t] = (int)(p >> 32);
    int e = (int)(p & 0xFFFFFFFFull);
    const float4* er = (const float4*)(ea + (size_t)e * 16);
    float4 v0 = er[0], v1 = er[1], v2 = er[2], v3 = er[3];
    __half2 h0 = __floats2half2_rn(v0.x, v0.y), h1 = __floats2half2_rn(v0.z, v0.w);
    __half2 h2 = __floats2half2_rn(v1.x, v1.y), h3 = __floats2half2_rn(v1.z, v1.w);
    __half2 h4 = __floats2half2_rn(v2.x, v2.y), h5 = __floats2half2_rn(v2.z, v2.w);
    __half2 h6 = __floats2half2_rn(v3.x, v3.y), h7 = __floats2half2_rn(v3.z, v3.w);
    uint4 a = make_uint4(*(unsigned*)&h0, *(unsigned*)&h1,
                         *(unsigned*)&h2, *(unsigned*)&h3);
    uint4 bb = make_uint4(*(unsigned*)&h4, *(unsigned*)&h5,
                          *(unsigned*)&h6, *(unsigned*)&h7);
    uint4* o = (uint4*)(ea_h + (size_t)t * 16);
    o[0] = a;
    o[1] = bb;
}

__global__ void k_gbound(const int* __restrict__ batch, int* __restrict__ gstart) {
    int n = blockIdx.x * blockDim.x + threadIdx.x;
    if (n >= Nn) return;
    int b = batch[n];
    if (n == 0) { for (int g = 0; g <= b; ++g) gstart[g] = 0; }
    else { int bp = batch[n - 1]; for (int g = bp + 1; g <= b; ++g) gstart[g] = n; }
    if (n == Nn - 1) { for (int g = b + 1; g <= Gg; ++g) gstart[g] = Nn; }
}

// ---------------- node kernels ----------------
__global__ __launch_bounds__(256) void k_encode(const float* __restrict__ x,
                         const float* __restrict__ Wn,
                         const float* __restrict__ bn, float* __restrict__ h) {
    __shared__ float sx[64 * 32];
    int base = blockIdx.x * 64;
    for (int i = threadIdx.x; i < 512; i += 256) {
        int off = i * 4, row = off >> 5;
        float4 v = (base + row < Nn) ? ((const float4*)(x))[(base * 32 + off) >> 2]
                                     : make_float4(0.f, 0.f, 0.f, 0.f);
        ((float4*)sx)[i] = v;
    }
    __syncthreads();
    int lane = threadIdx.x & 63, wv = threadIdx.x >> 6;
    float acc[16];
    float b = bn[lane];
#pragma unroll
    for (int nn = 0; nn < 16; ++nn) acc[nn] = b;
#pragma unroll 1
    for (int k0 = 0; k0 < 32; k0 += 4) {
        float w0 = Wn[(k0 + 0) * 64 + lane];
        float w1 = Wn[(k0 + 1) * 64 + lane];
        float w2 = Wn[(k0 + 2) * 64 + lane];
        float w3 = Wn[(k0 + 3) * 64 + lane];
#pragma unroll
        for (int nn = 0; nn < 16; ++nn) {
            int row = wv * 16 + nn;
            float4 hv = *(const float4*)&sx[row * 32 + k0];
            acc[nn] = fmaf(hv.x, w0, fmaf(hv.y, w1, fmaf(hv.z, w2, fmaf(hv.w, w3, acc[nn]))));
        }
    }
#pragma unroll
    for (int nn = 0; nn < 16; ++nn) {
        int n = base + wv * 16 + nn;
        if (n < Nn) h[(size_t)n * 64 + lane] = fmaxf(acc[nn], 0.f);
    }
}

// All 3 layers' Wqm/bqm (fp32) in one launch (block = layer).
__global__ void k_wqm3(const float* __restrict__ Wq_all, const float* __restrict__ bq_all,
                       const float* __restrict__ We_all, float* __restrict__ Wqm3,
                       float* __restrict__ bqm3) {
    int l = blockIdx.x;
    const float* Wq = Wq_all + l * 4096;
    const float* bq = bq_all + l * 64;
    const float* We = We_all + l * 1024;
    float* Wqm = Wqm3 + l * 4096;
    float* bqm = bqm3 + l * 64;
    for (int o = threadIdx.x; o < 64 * 64; o += 256) {
        int j = o >> 6, lp = o & 63, hh = lp >> 4, ii = lp & 15;
        float acc = 0.f;
#pragma unroll
        for (int c = 0; c < 16; ++c)
            acc += Wq[j * 64 + hh * 16 + c] * We[ii * 64 + hh * 16 + c];
        Wqm[o] = acc;
    }
    if (threadIdx.x < 64) {
        int hh = threadIdx.x >> 4, ii = threadIdx.x & 15;
        float acc = 0.f;
#pragma unroll
        for (int c = 0; c < 16; ++c)
            acc += bq[hh * 16 + c] * We[ii * 64 + hh * 16 + c];
        bqm[threadIdx.x] = acc;
    }
}

// Pack fp16 pair-interleaved weights: P[(k>>1)*128 + 2*col + (k&1)] = W[k][col].
// SC*log2e folded into Wq and Wqm (q,t then carry the alpha scale, so k_layer
// loads them raw). grid = 3 layers x 5 mats. mats: 0=Wq*SC 1=Wk 2=Wv 3=Wqm*SC 4=Ws.
__global__ void k_pack(const float* __restrict__ Wq, const float* __restrict__ Wk,
                       const float* __restrict__ Wv, const float* __restrict__ Wqm3,
                       const float* __restrict__ Ws, __half* __restrict__ pw) {
    int l = blockIdx.x / 5, m = blockIdx.x % 5;
    const float SC = 0.25f * 1.4426950408889634f;  // 1/sqrt(C) * log2(e)
    const float* src;
    float sc = 1.f;
    if (m == 0)      { src = Wq + l * 4096;   sc = SC; }
    else if (m == 1) { src = Wk + l * 4096; }
    else if (m == 2) { src = Wv + l * 4096; }
    else if (m == 3) { src = Wqm3 + l * 4096; sc = SC; }
    else             { src = Ws + l * 4096; }
    __half* dst = pw + ((size_t)l * 5 + m) * 4096;
    for (int i = threadIdx.x; i < 4096; i += 256) {
        int k = i >> 6, c = i & 63;
        dst[(k >> 1) * 128 + 2 * c + (k & 1)] = __float2half_rn(src[i] * sc);
    }
}

// fdot2 5-in-1 GEMM: h staged fp16 in LDS (half the traffic), weights from
// packed fp16 pairs, v_dot2_f32_f16 accumulate (half the fma of R5's fp32
// path). q,t stored fp16 (consumed only as fp16 by k_layer; SC pre-folded).
__global__ __launch_bounds__(256) void k_qkvt2(const float* __restrict__ h,
                       const __half* __restrict__ pw,
                       const float* __restrict__ bq, const float* __restrict__ bk,
                       const float* __restrict__ bv, const float* __restrict__ bqm,
                       const float* __restrict__ bs,
                       __half* __restrict__ qn16, __half* __restrict__ kv,
                       __half* __restrict__ tq16, float* __restrict__ sn) {
    __shared__ __half sh[64 * 64];
    int base = blockIdx.x * 64;
    for (int i = threadIdx.x; i < 1024; i += 256) {
        int off = i * 4, row = off >> 6;
        float4 v = (base + row < Nn) ? ((const float4*)(h))[((size_t)base * 64 + off) >> 2]
                                     : make_float4(0.f, 0.f, 0.f, 0.f);
        ((__half2*)sh)[i * 2]     = __floats2half2_rn(v.x, v.y);
        ((__half2*)sh)[i * 2 + 1] = __floats2half2_rn(v.z, v.w);
    }
    __syncthreads();
    int lane = threadIdx.x & 63, wv = threadIdx.x >> 6;
    const float SC = 0.25f * 1.4426950408889634f;
    const __half* Pq = pw;
    const __half* Pk = pw + 4096;
    const __half* Pv = pw + 8192;
    const __half* Pt = pw + 12288;
    const __half* Ps = pw + 16384;
    float aq[16], ak[16], av[16], at[16], as_[16];
    float _bq = bq[lane] * SC, _bk = bk[lane], _bv = bv[lane],
          _bt = bqm[lane] * SC, _bs = bs[lane];
#pragma unroll
    for (int nn = 0; nn < 16; ++nn) {
        aq[nn] = _bq; ak[nn] = _bk; av[nn] = _bv; at[nn] = _bt; as_[nn] = _bs;
    }
#pragma unroll 1
    for (int k0 = 0; k0 < 64; k0 += 4) {
        int pi = (k0 >> 1) * 128 + 2 * lane;
        f16x2 wq0 = *(const f16x2*)(Pq + pi), wq1 = *(const f16x2*)(Pq + pi + 128);
        f16x2 wk0 = *(const f16x2*)(Pk + pi), wk1 = *(const f16x2*)(Pk + pi + 128);
        f16x2 wv0 = *(const f16x2*)(Pv + pi), wv1 = *(const f16x2*)(Pv + pi + 128);
        f16x2 wt0 = *(const f16x2*)(Pt + pi), wt1 = *(const f16x2*)(Pt + pi + 128);
        f16x2 ws0 = *(const f16x2*)(Ps + pi), ws1 = *(const f16x2*)(Ps + pi + 128);
#pragma unroll
        for (int nn = 0; nn < 16; ++nn) {
            int row = wv * 16 + nn;
            f16x4 hv = *(const f16x4*)&sh[row * 64 + k0];
            f16x2 h01 = __builtin_shufflevector(hv, hv, 0, 1);
            f16x2 h23 = __builtin_shufflevector(hv, hv, 2, 3);
            aq[nn]  = fdot2f(h01, wq0, fdot2f(h23, wq1, aq[nn]));
            ak[nn]  = fdot2f(h01, wk0, fdot2f(h23, wk1, ak[nn]));
            av[nn]  = fdot2f(h01, wv0, fdot2f(h23, wv1, av[nn]));
            at[nn]  = fdot2f(h01, wt0, fdot2f(h23, wt1, at[nn]));
            as_[nn] = fdot2f(h01, ws0, fdot2f(h23, ws1, as_[nn]));
        }
    }
#pragma unroll
    for (int nn = 0; nn < 16; ++nn) {
        int n = base + wv * 16 + nn;
        if (n < Nn) {
            size_t o = (size_t)n * 64 + lane;
            qn16[o] = __float2half_rn(aq[nn]);
            tq16[o] = __float2half_rn(at[nn]);
            sn[o] = as_[nn];
            kv[(size_t)n * 128 + lane]      = __float2half_rn(ak[nn]);
            kv[(size_t)n * 128 + 64 + lane] = __float2half_rn(av[nn]);
        }
    }
}

// ---- edge pass v5: fp16 q/t (scale pre-folded), 16 nodes/block ----
// R5 overhead audit: one node per wave (= 4 inner iters) pays full prologue
// (2 float4 loads + 8 cvt) and each of 12500 blocks re-stages 4KB We (51MB
// redundant reads + barrier). Now: q/t are single 8B fp16 loads (no cvt, no
// scale), 4 nodes per wave amortize the We stage 4x.
__global__ __launch_bounds__(256) void k_layer5(float* __restrict__ h,
                      const __half* __restrict__ qn16, const __half* __restrict__ kv,
                      const __half* __restrict__ tq16, const float* __restrict__ sn,
                      const int* __restrict__ row_ptr, const int* __restrict__ src_perm,
                      const __half* __restrict__ eah, const float* __restrict__ We) {
    __shared__ float sWe[1024];
    __shared__ float tE[4][64];
    __shared__ float tV[4][64];
    for (int t = threadIdx.x; t < 1024; t += 256) sWe[t] = We[t];
    __syncthreads();
    int lane = threadIdx.x & 63, wv = threadIdx.x >> 6;
    int slot = lane >> 4, sl = lane & 15;
    int hh = lane >> 4;
    const int xoff = 4 * (sl & 3);                 // within-head x offset
#pragma unroll 1
    for (int j = 0; j < 4; ++j) {
        int n = blockIdx.x * 16 + wv * 4 + j;
        if (n >= Nn) break;                        // wave-uniform
        int beg = row_ptr[n], end = row_ptr[n + 1];
        f16x4 qv = *(const f16x4*)(qn16 + (size_t)n * 64 + 4 * sl);
        f16x4 tv = *(const f16x4*)(tq16 + (size_t)n * 64 + 4 * sl);
        f16x2 qa = __builtin_shufflevector(qv, qv, 0, 1);
        f16x2 qb = __builtin_shufflevector(qv, qv, 2, 3);
        f16x2 ta = __builtin_shufflevector(tv, tv, 0, 1);
        f16x2 tb = __builtin_shufflevector(tv, tv, 2, 3);
        float accd = 0.f;
        float4 accv = make_float4(0.f, 0.f, 0.f, 0.f);
        float4 acce = make_float4(0.f, 0.f, 0.f, 0.f);
        for (int idx = beg; idx < end; idx += 8) {
            int e0 = idx + slot, e1 = idx + 4 + slot;
            bool ok0 = e0 < end, ok1 = e1 < end;
            int i0 = ok0 ? e0 : beg, i1 = ok1 ? e1 : beg;
            int s0 = src_perm[i0], s1 = src_perm[i1];
            f16x4 k0 = *(const f16x4*)(kv + (size_t)s0 * 128 + 4 * sl);
            f16x4 v0 = *(const f16x4*)(kv + (size_t)s0 * 128 + 64 + 4 * sl);
            f16x4 k1 = *(const f16x4*)(kv + (size_t)s1 * 128 + 4 * sl);
            f16x4 v1 = *(const f16x4*)(kv + (size_t)s1 * 128 + 64 + 4 * sl);
            f16x4 x0 = *(const f16x4*)(eah + (size_t)i0 * 16 + xoff);
            f16x4 x1 = *(const f16x4*)(eah + (size_t)i1 * 16 + xoff);
            // dot over this lane's 4 channels; init -6 => -24 after 4-lane reduce
            float a0 = fdot2f(qa, __builtin_shufflevector(k0, k0, 0, 1),
                       fdot2f(qb, __builtin_shufflevector(k0, k0, 2, 3),
                       fdot2f(ta, __builtin_shufflevector(x0, x0, 0, 1),
                       fdot2f(tb, __builtin_shufflevector(x0, x0, 2, 3), -6.0f))));
            float a1 = fdot2f(qa, __builtin_shufflevector(k1, k1, 0, 1),
                       fdot2f(qb, __builtin_shufflevector(k1, k1, 2, 3),
                       fdot2f(ta, __builtin_shufflevector(x1, x1, 0, 1),
                       fdot2f(tb, __builtin_shufflevector(x1, x1, 2, 3), -6.0f))));
            a0 += __shfl_xor(a0, 1, 4); a1 += __shfl_xor(a1, 1, 4);
            a0 += __shfl_xor(a0, 2, 4); a1 += __shfl_xor(a1, 2, 4);
            float p0 = ok0 ? __builtin_exp2f(a0) : 0.f;
            float p1 = ok1 ? __builtin_exp2f(a1) : 0.f;
            accd += p0 + p1;
            accv.x = fmaf(p0, (float)v0[0], fmaf(p1, (float)v1[0], accv.x));
            accv.y = fmaf(p0, (float)v0[1], fmaf(p1, (float)v1[1], accv.y));
            accv.z = fmaf(p0, (float)v0[2], fmaf(p1, (float)v1[2], accv.z));
            accv.w = fmaf(p0, (float)v0[3], fmaf(p1, (float)v1[3], accv.w));
            acce.x = fmaf(p0, (float)x0[0], fmaf(p1, (float)x1[0], acce.x));
            acce.y = fmaf(p0, (float)x0[1], fmaf(p1, (float)x1[1], acce.y));
            acce.z = fmaf(p0, (float)x0[2], fmaf(p1, (float)x1[2], acce.z));
            acce.w = fmaf(p0, (float)x0[3], fmaf(p1, (float)x1[3], acce.w));
        }
        // merge the 4 independent slots (shared fixed shift -> plain adds)
        accd   += __shfl_xor(accd, 16);   accd   += __shfl_xor(accd, 32);
        accv.x += __shfl_xor(accv.x, 16); accv.x += __shfl_xor(accv.x, 32);
        accv.y += __shfl_xor(accv.y, 16); accv.y += __shfl_xor(accv.y, 32);
        accv.z += __shfl_xor(accv.z, 16); accv.z += __shfl_xor(accv.z, 32);
        accv.w += __shfl_xor(accv.w, 16); accv.w += __shfl_xor(accv.w, 32);
        acce.x += __shfl_xor(acce.x, 16); acce.x += __shfl_xor(acce.x, 32);
        acce.y += __shfl_xor(acce.y, 16); acce.y += __shfl_xor(acce.y, 32);
        acce.z += __shfl_xor(acce.z, 16); acce.z += __shfl_xor(acce.z, 32);
        acce.w += __shfl_xor(acce.w, 16); acce.w += __shfl_xor(acce.w, 32);
        float inv = 1.f / (accd + 1e-16f);
        if (slot == 0) {
            ((float4*)tE[wv])[sl] = make_float4(acce.x * inv, acce.y * inv,
                                                acce.z * inv, acce.w * inv);
            ((float4*)tV[wv])[sl] = make_float4(accv.x * inv, accv.y * inv,
                                                accv.z * inv, accv.w * inv);
        }
        // wave-lockstep LDS round-trip (same wave wrote it; no barrier)
        float re = 0.f;
#pragma unroll
        for (int i = 0; i < 16; ++i)
            re = fmaf(tE[wv][hh * 16 + i], sWe[i * 64 + lane], re);
        size_t o = (size_t)n * 64 + lane;
        float hv = h[o];
        h[o] = hv + fmaxf(tV[wv][lane] + re + sn[o], 0.f);
    }
}

// legacy edge pass (fallback mode 0 only: fp32 ea gather via eperm).
// q/t now fp16 with SC pre-folded (no scale here).
__global__ __launch_bounds__(256) void k_layer(float* __restrict__ h,
                      const __half* __restrict__ qn16, const __half* __restrict__ kv,
                      const __half* __restrict__ tq16, const float* __restrict__ sn,
                      const int* __restrict__ row_ptr, const int* __restrict__ src_perm,
                      const int* __restrict__ eperm, const float* __restrict__ eaf,
                      const float* __restrict__ We) {
    __shared__ float sWe[1024];
    __shared__ float tile[4][64];
    for (int t = threadIdx.x; t < 1024; t += 256) sWe[t] = We[t];
    __syncthreads();
    int lane = threadIdx.x & 63, wv = threadIdx.x >> 6;
    int hh = lane >> 4, cc = lane & 15;
    int n = blockIdx.x * 4 + wv;
    if (n >= Nn) return;
    int beg = row_ptr[n], end = row_ptr[n + 1];
    float q = __half2float(qn16[(size_t)n * 64 + lane]);
    float t = __half2float(tq16[(size_t)n * 64 + lane]);
    float m = -INFINITY, accd = 0.f, accv = 0.f, acce = 0.f;
    int idx = beg;
    for (; idx < end; ++idx) {
        long b0 = (long)src_perm[idx] * 128;
        float k0 = __half2float(kv[b0 + lane]);
        float v0 = __half2float(kv[b0 + 64 + lane]);
        float x0 = eaf[(long)eperm[idx] * 16 + cc];
        float a0 = fmaf(q, k0, x0 * t);
        a0 += __shfl_xor(a0, 1, 16);
        a0 += __shfl_xor(a0, 2, 16);
        a0 += __shfl_xor(a0, 4, 16);
        a0 += __shfl_xor(a0, 8, 16);
        float nm = fmaxf(m, a0);
        float w = __builtin_exp2f(m - nm);
        float p0 = __builtin_exp2f(a0 - nm);
        accd = fmaf(accd, w, p0);
        accv = fmaf(accv, w, p0 * v0);
        acce = fmaf(acce, w, p0 * x0);
        m = nm;
    }
    float inv = 1.f / (accd + 1e-16f);
    tile[wv][lane] = acce * inv;
    float re = 0.f;
#pragma unroll
    for (int i = 0; i < 16; ++i)
        re = fmaf(tile[wv][hh * 16 + i], sWe[i * 64 + lane], re);
    size_t o = (size_t)n * 64 + lane;
    float hv = h[o];
    h[o] = hv + fmaxf(fmaf(accv, inv, re + sn[o]), 0.f);
}

__global__ void k_pool(const float* __restrict__ h, const int* __restrict__ gstart,
                       const float* __restrict__ W1, const float* __restrict__ b1,
                       const float* __restrict__ W2, const float* __restrict__ b2,
                       float* __restrict__ out) {
    int g = blockIdx.x;
    int lane = threadIdx.x & 63, wv = threadIdx.x >> 6;
    int beg = gstart[g], end = gstart[g + 1];
    __shared__ float red[4][64];
    __shared__ float sp[64];
    __shared__ float sh[32];
    float acc = 0.f;
    for (int n = beg + wv; n < end; n += 4) acc += h[(size_t)n * 64 + lane];
    red[wv][lane] = acc;
    __syncthreads();
    if (threadIdx.x < 64) {
        float c = fmaxf((float)(end - beg), 1.f);
        sp[lane] = (red[0][lane] + red[1][lane] + red[2][lane] + red[3][lane]) / c;
    }
    __syncthreads();
    if (threadIdx.x < 32) {
        int t = threadIdx.x;
        float a = b1[t];
#pragma unroll
        for (int i = 0; i < 64; ++i) a = fmaf(sp[i], W1[i * 32 + t], a);
        sh[t] = fmaxf(a, 0.f) * W2[t];
    }
    __syncthreads();
    if (threadIdx.x == 0) {
        float s = b2[0];
#pragma unroll
        for (int i = 0; i < 32; ++i) s += sh[i];
        out[g] = s;
    }
}

extern "C" void kernel_launch(void* const* d_in, const int* in_sizes, int n_in,
                              void* d_out, int out_size, void* d_ws, size_t ws_size,
                              hipStream_t stream) {
    const float* x   = (const float*)d_in[0];
    const int*   ei  = (const int*)d_in[1];
    const float* ea  = (const float*)d_in[2];
    const int*   bat = (const int*)d_in[3];
    const float* Wn  = (const float*)d_in[4];
    const float* bn  = (const float*)d_in[5];
    const float* Wq  = (const float*)d_in[6];
    const float* bq  = (const float*)d_in[7];
    const float* Wk  = (const float*)d_in[8];
    const float* bk  = (const float*)d_in[9];
    const float* Wv  = (const float*)d_in[10];
    const float* bv  = (const float*)d_in[11];
    const float* We  = (const float*)d_in[12];
    const float* Wsk = (const float*)d_in[13];
    const float* bs  = (const float*)d_in[14];
    const float* W1  = (const float*)d_in[15];
    const float* b1  = (const float*)d_in[16];
    const float* W2  = (const float*)d_in[17];
    const float* b2  = (const float*)d_in[18];
    float* out = (float*)d_out;

    const size_t NH = (size_t)Nn * 64;
    float* h    = (float*)d_ws;
    float* qn   = h + NH;                      // fp16 q (uses half the slot)
    float* tq   = h + 2 * NH;                  // fp16 t
    float* sn   = h + 3 * NH;
    __half* kv  = (__half*)(h + 4 * NH);       // N*128 half == NH floats of space
    float* Wqm3 = h + 5 * NH;                  // 3*4096
    float* bqm3 = Wqm3 + 3 * 4096;             // 3*64
    __half* pw  = (__half*)(bqm3 + 3 * 64);    // 3*5*4096 packed fp16 weights
    int* deg       = (int*)(pw + 3 * 5 * 4096);   // N (legacy)
    int* row_ptr   = deg + Nn;                 // N+1
    int* cursor    = row_ptr + Nn + 1;         // N (legacy)
    int* src_perm  = cursor + Nn;              // E
    int* eperm     = src_perm + Ee;            // E (legacy fallback only)
    int* bsum      = eperm + Ee;               // 256 (legacy)
    int* gstart    = bsum + 256;               // G+1
    char* pe = (char*)(gstart + Gg + 1);
    __half* ea_h = (__half*)(((uintptr_t)pe + 63) & ~(uintptr_t)63);   // E*16 half
    char* pt = (char*)(ea_h + (size_t)Ee * 16);
    unsigned long long* tmp =
        (unsigned long long*)(((uintptr_t)pt + 15) & ~(uintptr_t)15);  // E u64
    size_t need_eah = ((char*)(ea_h + (size_t)Ee * 16)) - (char*)d_ws;
    size_t need_tmp = ((char*)(tmp + Ee)) - (char*)d_ws;
    // CSR-build scratch overlaid on qn/tq/sn (dead until k_qkvt2, and the
    // CSR build fully completes before k_qkvt2 in stream order):
    unsigned long long* tmp2 = (unsigned long long*)qn;  // E u64 == NH floats exactly
    int* table   = (int*)tq;                             // NBK*NTB ints (~613 KB)
    int* bktsz   = (int*)sn;                             // NBK
    int* bktbase = bktsz + 256;                          // NBK+1
    __half* qn16 = (__half*)qn;
    __half* tq16 = (__half*)tq;
    // mode 2: zero-global-atomic counting-sort CSR build (fast).
    // mode 1: legacy scatter + easort. mode 0: legacy scatter, fp32 ea gather.
    int mode = (ws_size >= need_tmp) ? 2 : (ws_size >= need_eah) ? 1 : 0;

    if (mode == 2) {
        k_cnt<<<NTB, 256, 0, stream>>>(ei, table);
        k_colscan<<<NBK, 256, 0, stream>>>(table, bktsz);
        k_bktscan<<<1, 256, 0, stream>>>(bktsz, bktbase);
        k_binfill<<<NTB, 256, 0, stream>>>(ei, table, bktbase, tmp);
        k_bktB<<<NBK, 256, 0, stream>>>(tmp, bktbase, row_ptr, tmp2);
        k_scatB<<<(Ee + 255) / 256, 256, 0, stream>>>(tmp2, src_perm, ea, ea_h);
    } else {
        const int NB = 196;  // ceil(50000/256)
        hipMemsetAsync(deg, 0, Nn * sizeof(int), stream);
        k_hist<<<(Ee + 255) / 256, 256, 0, stream>>>(ei, deg);
        k_scan1<<<NB, 256, 0, stream>>>(deg, row_ptr, bsum);
        k_scan2<<<1, 256, 0, stream>>>(bsum, NB);
        k_scan3<<<(Nn + 256) / 256, 256, 0, stream>>>(row_ptr, bsum);
        hipMemcpyAsync(cursor, row_ptr, Nn * sizeof(int), hipMemcpyDeviceToDevice, stream);
        k_scatter<<<(Ee + 255) / 256, 256, 0, stream>>>(ei, cursor, src_perm, eperm);
        if (mode == 1)
            k_easort<<<((long)Ee * 4 + 255) / 256, 256, 0, stream>>>(ea, eperm, ea_h);
    }
    k_gbound<<<(Nn + 255) / 256, 256, 0, stream>>>(bat, gstart);
    k_wqm3<<<3, 256, 0, stream>>>(Wq, bq, We, Wqm3, bqm3);
    k_pack<<<15, 256, 0, stream>>>(Wq, Wk, Wv, Wqm3, Wsk, pw);

    int nodeBlocks = (Nn + 63) / 64;
    k_encode<<<nodeBlocks, 256, 0, stream>>>(x, Wn, bn, h);
    for (int l = 0; l < 3; ++l) {
        k_qkvt2<<<nodeBlocks, 256, 0, stream>>>(h, pw + (size_t)l * 5 * 4096,
                                                bq + l * 64, bk + l * 64, bv + l * 64,
                                                bqm3 + l * 64, bs + l * 64,
                                                qn16, kv, tq16, sn);
        if (mode >= 1)
            k_layer5<<<(Nn + 15) / 16, 256, 0, stream>>>(h, qn16, kv, tq16, sn,
                    row_ptr, src_perm, ea_h, We + l * 1024);
        else
            k_layer<<<(Nn + 3) / 4, 256, 0, stream>>>(h, qn16, kv, tq16, sn,
                    row_ptr, src_perm, eperm, ea, We + l * 1024);
    }
    k_pool<<<Gg, 256, 0, stream>>>(h, gstart, W1, b1, W2, b2, out);
}